// Round 9
// baseline (481.520 us; speedup 1.0000x reference)
//
#include <hip/hip_runtime.h>
#include <hip/hip_bf16.h>
#include <math.h>

#define B_    64
#define L_    512
#define C_    321
#define PRED_ 96
#define N_    64
#define HID_  32
#define BC_   (B_*C_)   // 20544
#define SROW_ 528
#define EPS_  1e-5f
#define ALPHA_ 0.2f
#define GR_   16
#define RB_   8
#define NBLK2_ (BC_/GR_) // 1284
#define D64_  6.2771017353866808e-7f   // 0.8^64

typedef __attribute__((ext_vector_type(8))) short bf16x8;
typedef __attribute__((ext_vector_type(4))) float f32x4;

// Fast gelu: A&S 7.1.26 erf approx, |eps|<=1.5e-7, branch-free.
__device__ __forceinline__ float gelu_f(float x){
  float ax = fabsf(x);
  float z  = ax * 0.70710678118654752440f;
  float t  = __builtin_amdgcn_rcpf(fmaf(0.3275911f, z, 1.0f));
  float poly = fmaf(fmaf(fmaf(fmaf(1.061405429f, t, -1.453152027f),
                   t, 1.421413741f), t, -0.284496736f), t, 0.254829592f) * t;
  float e  = __expf(-z*z);
  float erfp = fmaf(-poly, e, 1.0f);
  return fmaf(0.5f*ax, erfp, 0.5f*x);
}
__device__ __forceinline__ unsigned short bf16bits(float x){
  __hip_bfloat16 h = __float2bfloat16(x);
  return *(unsigned short*)&h;
}

// ---------- K0: fold seas/tr matmuls through fus; bf16 col-major [j][k] ----------
__global__ __launch_bounds__(256) void k0_fold(
    const float* __restrict__ seas_w, const float* __restrict__ tr_w,
    const float* __restrict__ fus_w,
    __hip_bfloat16* __restrict__ Wsf, __hip_bfloat16* __restrict__ Wtf) {
  int idx = blockIdx.x*256 + threadIdx.x;
  if (idx >= 96*1536) return;
  int j = idx / 1536, k = idx - j*1536;
  float acc = 0.f;
  if (k < 1024) {
    for (int i=0;i<96;++i) acc = fmaf(fus_w[j*192+i], seas_w[i*1024+k], acc);
    Wsf[(size_t)j*1024 + k] = __float2bfloat16(acc);
  } else {
    int l = k - 1024;
    for (int i=0;i<96;++i) acc = fmaf(fus_w[j*192+96+i], tr_w[i*512+l], acc);
    Wtf[(size_t)j*512 + l] = __float2bfloat16(acc);
  }
}

// ---------- K0b: bias fold + tr colsum + fc2 transpose/colsum ----------
__global__ void k0b_bias(
    const float* __restrict__ seas_b, const float* __restrict__ tr_b,
    const float* __restrict__ fus_w, const float* __restrict__ fus_b,
    const float* __restrict__ tr_w, const float* __restrict__ fc2_w,
    float* __restrict__ biasc, float* __restrict__ colsumT,
    float* __restrict__ fc2T, float* __restrict__ fc2cs) {
  __shared__ float rowsum[96];
  int t = threadIdx.x;
  if (t < 96) {
    float s = 0.f;
    for (int l=0;l<512;++l) s += tr_w[t*512+l];
    rowsum[t] = s;
  }
  // fc2T[k*16+p] = fc2_w[p*32+k]
  for (int idx=t; idx<512; idx+=128)
    fc2T[idx] = fc2_w[(idx&15)*32 + (idx>>4)];
  if (t < 16) {
    float s = 0.f;
    for (int k=0;k<32;++k) s += fc2_w[t*32+k];
    fc2cs[t] = s;
  }
  __syncthreads();
  if (t < 96) {
    float acc = fus_b[t], cs = 0.f;
    for (int i=0;i<96;++i) {
      acc = fmaf(fus_w[t*192+i],    seas_b[i], acc);
      acc = fmaf(fus_w[t*192+96+i], tr_b[i],   acc);
      cs  = fmaf(fus_w[t*192+96+i], rowsum[i], cs);
    }
    biasc[t] = acc; colsumT[t] = cs;
  }
}

// ---------- K1: RevIN + EMA, single x read, reconstructed pass-B, vector stores ----------
__global__ __launch_bounds__(256) void k1_revin_ema(
    const float* __restrict__ x, const float* __restrict__ rev_w, const float* __restrict__ rev_b,
    float* __restrict__ s_raw, __hip_bfloat16* __restrict__ t_bf, float* __restrict__ rowpar,
    float* __restrict__ pooled) {
  __shared__ float lf[8][32];
  __shared__ float psum[8][32], psq[8][32];
  __shared__ float sb[8][32][16];
  int tid = threadIdx.x;
  int q = tid >> 5, r = tid & 31;
  int row = blockIdx.x*32 + r;
  int b = row / C_, c = row - b*C_;
  const float* xp = x + (size_t)b*L_*C_ + c;
  int l0 = q*64;
  float sreg[64];
  float loc = 0.f, sum = 0.f, sq = 0.f;
  #pragma unroll
  for (int i=0;i<64;++i) {
    float v = xp[(size_t)(l0+i)*C_];
    sum += v; sq = fmaf(v,v,sq);
    loc = (q==0 && i==0) ? v : fmaf(ALPHA_, v, 0.8f*loc);
    sreg[i] = loc;
  }
  lf[q][r] = loc; psum[q][r] = sum; psq[q][r] = sq;
  __syncthreads();
  float cin = 0.f;
  for (int j=0;j<q;++j) cin = fmaf(D64_, cin, lf[j][r]);
  float S=0.f, Q=0.f;
  #pragma unroll
  for (int qq=0;qq<8;++qq){ S += psum[qq][r]; Q += psq[qq][r]; }
  float mean = S*(1.0f/512.0f);
  float var  = (Q - S*S*(1.0f/512.0f))*(1.0f/511.0f);
  var = fmaxf(var, 0.f);
  float stdv = sqrtf(var) + EPS_;
  float rwc = rev_w[c];
  float a = rwc / stdv;
  if (q==0) {
    float rbc = rev_b[c];
    float g = rbc - mean*a;
    float inva = stdv / rwc;
    ((float4*)rowpar)[row] = make_float4(a, g, mean, inva);
  }
  float prev = 0.f, f = 1.f;
  float sv4[4];
  unsigned tpack[4];
  #pragma unroll
  for (int i=0;i<64;++i) {
    float lc = sreg[i];
    f *= 0.8f;
    float tt = fmaf(f, cin, lc);
    float s = (q==0 && i==0) ? 0.f : fmaf(4.f, lc - prev, -f*cin);
    prev = lc;
    float sv = s * a;
    sreg[i] = sv;
    if (i < 16) sb[q][r][i] = sv;
    sv4[i&3] = sv;
    if ((i&3)==3)
      *(float4*)&s_raw[(size_t)row*SROW_ + l0 + i - 3] = make_float4(sv4[0],sv4[1],sv4[2],sv4[3]);
    unsigned hb = bf16bits(tt * a);
    if ((i&1)==0) tpack[(i>>1)&3] = hb; else tpack[(i>>1)&3] |= (hb<<16);
    if ((i&7)==7)
      *(uint4*)&t_bf[(size_t)row*512 + l0 + i - 7] = make_uint4(tpack[0],tpack[1],tpack[2],tpack[3]);
  }
  if (q==7) {
    float slast = sreg[63];
    *(float4*)&s_raw[(size_t)row*SROW_ + 512] = make_float4(slast,slast,slast,slast);
    *(float4*)&s_raw[(size_t)row*SROW_ + 516] = make_float4(slast,slast,slast,slast);
  }
  __syncthreads();
  #pragma unroll
  for (int j=0;j<7;++j) {
    float s = 0.f;
    #pragma unroll
    for (int p=0;p<16;++p) s += sreg[j*8+p];
    pooled[(size_t)row*64 + q*8 + j] = s*(1.0f/16.0f);
  }
  {
    float s = 0.f;
    #pragma unroll
    for (int p=0;p<8;++p) s += sreg[56+p];
    if (q < 7) {
      #pragma unroll
      for (int p=0;p<8;++p) s += sb[q+1][r][p];
    } else {
      s += 8.0f * sreg[63];
    }
    pooled[(size_t)row*64 + q*8 + 7] = s*(1.0f/16.0f);
  }
}

// ---------- K4: gate MLP ----------
__global__ __launch_bounds__(256) void k4_gate(
    const float* __restrict__ pooled,
    const float* __restrict__ m1_w, const float* __restrict__ m1_b,
    const float* __restrict__ m2_w, const float* __restrict__ m2_b,
    float* __restrict__ wl_g) {
  __shared__ float pl[64][65];
  __shared__ float h1[64][129];
  int t = threadIdx.x;
  int row0 = blockIdx.x*64;
  for (int idx=t; idx<4096; idx+=256)
    pl[idx>>6][idx&63] = pooled[(size_t)row0*64 + idx];
  __syncthreads();
  int w = t>>6, l = t&63;
  for (int ii=0; ii<32; ++ii) {
    int i = w*32 + ii;
    float acc = m1_b[i];
    #pragma unroll
    for (int k=0;k<64;++k) acc = fmaf(pl[l][k], m1_w[i*64+k], acc);
    h1[l][i] = gelu_f(acc);
  }
  __syncthreads();
  for (int jj=0; jj<16; ++jj) {
    int n = w*16 + jj;
    float acc = m2_b[n];
    #pragma unroll
    for (int k=0;k<128;++k) acc = fmaf(h1[l][k], m2_w[n*128+k], acc);
    wl_g[(size_t)(row0+l)*64 + n] = 1.0f/(1.0f + __expf(-acc));
  }
}

// ---------- K2 (fallback): BN1 statistics ----------
__global__ __launch_bounds__(256) void k2_bn1stats(
    const float* __restrict__ s_raw,
    const float* __restrict__ fc1_w, const float* __restrict__ fc1_b,
    float* __restrict__ partials) {
  __shared__ float sl[GR_*SROW_];
  __shared__ float red[2][GR_*64];
  int t = threadIdx.x;
  int row0 = blockIdx.x*GR_;
  for (int idx=t; idx<GR_*520; idx+=256) {
    int rr = idx/520, cc = idx - rr*520;
    sl[rr*SROW_+cc] = s_raw[(size_t)(row0+rr)*SROW_+cc];
  }
  __syncthreads();
  int lr = t >> 4, ng = t & 15;
  for (int q=0;q<4;++q) {
    int n = ng + 16*q;
    float sp[16];
    #pragma unroll
    for (int p=0;p<16;++p) sp[p] = sl[lr*SROW_ + n*8 + p];
    float s1=0.f, s2=0.f;
    #pragma unroll
    for (int hid=0; hid<32; ++hid) {
      float acc = fc1_b[hid];
      #pragma unroll
      for (int p=0;p<16;++p) acc = fmaf(sp[p], fc1_w[hid*16+p], acc);
      float gv = gelu_f(acc);
      s1 += gv; s2 = fmaf(gv,gv,s2);
    }
    red[0][lr*64+n] = s1;
    red[1][lr*64+n] = s2;
  }
  __syncthreads();
  if (t < 64) {
    float S1=0.f, S2=0.f;
    for (int lr2=0; lr2<GR_; ++lr2) { S1 += red[0][lr2*64+t]; S2 += red[1][lr2*64+t]; }
    partials[((size_t)blockIdx.x*64+t)*2+0] = S1;
    partials[((size_t)blockIdx.x*64+t)*2+1] = S2;
  }
}

// ---------- K2v2: BN1 stats + materialize cr = conv3(gelu(fc1(s))) in bf16 ----------
__global__ __launch_bounds__(256) void k2v2_bn1_cr(
    const float* __restrict__ s_raw,
    const float* __restrict__ fc1_w, const float* __restrict__ fc1_b,
    const float* __restrict__ conv_w,
    float* __restrict__ partials, __hip_bfloat16* __restrict__ crp) {
  __shared__ float sl[GR_*SROW_];
  __shared__ float cw[192];
  __shared__ float red[2][GR_*64];
  int t = threadIdx.x;
  int row0 = blockIdx.x*GR_;
  if (t < 192) cw[t] = conv_w[t];
  for (int idx=t; idx<GR_*520; idx+=256) {
    int rr = idx/520, cc = idx - rr*520;
    sl[rr*SROW_+cc] = s_raw[(size_t)(row0+rr)*SROW_+cc];
  }
  __syncthreads();
  int lr = t >> 4, ng = t & 15;
  for (int q=0;q<4;++q) {
    int n = ng + 16*q;
    float sp[16];
    #pragma unroll
    for (int p=0;p<16;++p) sp[p] = sl[lr*SROW_ + n*8 + p];
    float w0=cw[n*3], wm=cw[n*3+1], wp=cw[n*3+2];
    float s1=0.f, s2=0.f;
    auto gf = [&](int k)->float {
      float acc = fc1_b[k];
      #pragma unroll
      for (int p=0;p<16;++p) acc = fmaf(sp[p], fc1_w[k*16+p], acc);
      float g = gelu_f(acc);
      s1 += g; s2 = fmaf(g,g,s2);
      return g;
    };
    float gm = 0.f, gc = gf(0), gp = gf(1);
    unsigned wds[16]; unsigned crlo = 0;
    #pragma unroll
    for (int k=0;k<32;++k) {
      float cr = fmaf(gm, w0, fmaf(gc, wm, (k<31) ? gp*wp : 0.f));
      unsigned hb = bf16bits(cr);
      if ((k&1)==0) crlo = hb; else wds[k>>1] = crlo | (hb<<16);
      gm = gc; gc = gp;
      gp = (k+2<32) ? gf(k+2) : 0.f;
    }
    uint4* dst = (uint4*)&crp[((size_t)(row0+lr)*64 + n)*32];
    dst[0] = make_uint4(wds[0],wds[1],wds[2],wds[3]);
    dst[1] = make_uint4(wds[4],wds[5],wds[6],wds[7]);
    dst[2] = make_uint4(wds[8],wds[9],wds[10],wds[11]);
    dst[3] = make_uint4(wds[12],wds[13],wds[14],wds[15]);
    red[0][lr*64+n] = s1;
    red[1][lr*64+n] = s2;
  }
  __syncthreads();
  if (t < 64) {
    float S1=0.f, S2=0.f;
    for (int lr2=0; lr2<GR_; ++lr2) { S1 += red[0][lr2*64+t]; S2 += red[1][lr2*64+t]; }
    partials[((size_t)blockIdx.x*64+t)*2+0] = S1;
    partials[((size_t)blockIdx.x*64+t)*2+1] = S2;
  }
}

// ---------- bn reduce ----------
__global__ __launch_bounds__(256) void k_bnreduce(
    const float* __restrict__ partials, int nblk,
    const float* __restrict__ bnw, const float* __restrict__ bnb,
    float* __restrict__ scale, float* __restrict__ shift) {
  __shared__ float red[2][256];
  int n = blockIdx.x, t = threadIdx.x;
  float s1=0.f, s2=0.f;
  for (int i=t; i<nblk; i+=256) {
    s1 += partials[((size_t)i*64+n)*2+0];
    s2 += partials[((size_t)i*64+n)*2+1];
  }
  red[0][t]=s1; red[1][t]=s2;
  __syncthreads();
  for (int off=128; off>0; off>>=1) {
    if (t<off) { red[0][t]+=red[0][t+off]; red[1][t]+=red[1][t+off]; }
    __syncthreads();
  }
  if (t==0) {
    const float count = (float)BC_ * 32.0f;
    float mu = red[0][0]/count;
    float var = red[1][0]/count - mu*mu;
    float sc = rsqrtf(var + EPS_) * bnw[n];
    scale[n] = sc;
    shift[n] = bnb[n] - mu*sc;
  }
}

// ---------- K3 (fallback): BN2 statistics ----------
__global__ __launch_bounds__(256) void k3_bn2stats(
    const float* __restrict__ s_raw,
    const float* __restrict__ fc1_w, const float* __restrict__ fc1_b,
    const float* __restrict__ scale1, const float* __restrict__ shift1,
    const float* __restrict__ conv_w, const float* __restrict__ conv_b,
    float* __restrict__ partials) {
  __shared__ float sl[GR_*SROW_];
  __shared__ float sc1[64], sh1[64], cw[192], cb[64];
  __shared__ float red[2][GR_*64];
  int t = threadIdx.x;
  int row0 = blockIdx.x*GR_;
  if (t < 64) { sc1[t]=scale1[t]; sh1[t]=shift1[t]; cb[t]=conv_b[t]; }
  if (t >= 64 && t < 256) cw[t-64] = conv_w[t-64];
  __syncthreads();
  for (int idx=t; idx<GR_*520; idx+=256) {
    int rr = idx/520, cc = idx - rr*520;
    sl[rr*SROW_+cc] = s_raw[(size_t)(row0+rr)*SROW_+cc];
  }
  __syncthreads();
  int lr = t >> 4, ng = t & 15;
  for (int q=0;q<4;++q) {
    int n = ng + 16*q;
    float sp[16];
    #pragma unroll
    for (int p=0;p<16;++p) sp[p] = sl[lr*SROW_ + n*8 + p];
    float scn = sc1[n], shn = sh1[n];
    float h[32];
    #pragma unroll
    for (int hid=0; hid<32; ++hid) {
      float acc = fc1_b[hid];
      #pragma unroll
      for (int p=0;p<16;++p) acc = fmaf(sp[p], fc1_w[hid*16+p], acc);
      h[hid] = fmaf(gelu_f(acc), scn, shn);
    }
    float w0=cw[n*3], wm=cw[n*3+1], wpp=cw[n*3+2], cbn=cb[n];
    float s1=0.f, s2=0.f, prev=0.f;
    #pragma unroll
    for (int k2=0;k2<32;++k2) {
      float cur = h[k2];
      float cv = cbn;
      cv = fmaf(prev, w0, cv);
      cv = fmaf(cur, wm, cv);
      if (k2<31) cv = fmaf(h[k2+1], wpp, cv);
      float gv = gelu_f(cv);
      s1 += gv; s2 = fmaf(gv,gv,s2);
      prev = cur;
    }
    red[0][lr*64+n]=s1; red[1][lr*64+n]=s2;
  }
  __syncthreads();
  if (t < 64) {
    float S1=0.f, S2=0.f;
    for (int lr2=0; lr2<GR_; ++lr2) { S1 += red[0][lr2*64+t]; S2 += red[1][lr2*64+t]; }
    partials[((size_t)blockIdx.x*64+t)*2+0] = S1;
    partials[((size_t)blockIdx.x*64+t)*2+1] = S2;
  }
}

// ---------- K3v2: BN2 stats from cr; writes g2 = gelu(bn1affine(cr)) IN PLACE ----------
__global__ __launch_bounds__(256) void k3v2_bn2stats(
    __hip_bfloat16* __restrict__ crp,
    const float* __restrict__ scale1, const float* __restrict__ shift1,
    const float* __restrict__ conv_w, const float* __restrict__ conv_b,
    float* __restrict__ partials) {
  __shared__ float sc1[64], sh0l[64], shml[64], sh31l[64];
  __shared__ float red[2][GR_*64];
  int t = threadIdx.x;
  int row0 = blockIdx.x*GR_;
  if (t < 64) {
    float w0=conv_w[t*3], wm=conv_w[t*3+1], wp=conv_w[t*3+2];
    float s1v=shift1[t], cbv=conv_b[t];
    sc1[t]  = scale1[t];
    sh0l[t] = fmaf(s1v, wm+wp, cbv);
    shml[t] = fmaf(s1v, w0+wm+wp, cbv);
    sh31l[t]= fmaf(s1v, w0+wm, cbv);
  }
  __syncthreads();
  int lr = t >> 4, ng = t & 15;
  for (int q=0;q<4;++q) {
    int n = ng + 16*q;
    uint4* crb = (uint4*)&crp[((size_t)(row0+lr)*64 + n)*32];
    uint4 u0=crb[0], u1=crb[1], u2=crb[2], u3=crb[3];
    unsigned uw[16] = {u0.x,u0.y,u0.z,u0.w, u1.x,u1.y,u1.z,u1.w,
                       u2.x,u2.y,u2.z,u2.w, u3.x,u3.y,u3.z,u3.w};
    float sc1n = sc1[n];
    float shm = shml[n];
    float s1=0.f, s2=0.f;
    unsigned wds[16];
    #pragma unroll
    for (int j=0;j<16;++j) {
      unsigned u = uw[j];
      float c0 = __uint_as_float(u<<16);
      float c1 = __uint_as_float(u & 0xffff0000u);
      float sh_0 = (j==0)  ? sh0l[n]  : shm;
      float sh_1 = (j==15) ? sh31l[n] : shm;
      float g0 = gelu_f(fmaf(c0, sc1n, sh_0));
      float g1 = gelu_f(fmaf(c1, sc1n, sh_1));
      s1 += g0 + g1;
      s2 = fmaf(g0,g0, fmaf(g1,g1, s2));
      wds[j] = (unsigned)bf16bits(g0) | (((unsigned)bf16bits(g1))<<16);
    }
    crb[0] = make_uint4(wds[0],wds[1],wds[2],wds[3]);
    crb[1] = make_uint4(wds[4],wds[5],wds[6],wds[7]);
    crb[2] = make_uint4(wds[8],wds[9],wds[10],wds[11]);
    crb[3] = make_uint4(wds[12],wds[13],wds[14],wds[15]);
    red[0][lr*64+n]=s1; red[1][lr*64+n]=s2;
  }
  __syncthreads();
  if (t < 64) {
    float S1=0.f, S2=0.f;
    for (int lr2=0; lr2<GR_; ++lr2) { S1 += red[0][lr2*64+t]; S2 += red[1][lr2*64+t]; }
    partials[((size_t)blockIdx.x*64+t)*2+0] = S1;
    partials[((size_t)blockIdx.x*64+t)*2+1] = S2;
  }
}

// ---------- K5a (fallback): full per-row pipeline ----------
__global__ __launch_bounds__(256) void k5a_pipeline(
    const float* __restrict__ s_raw, const float* __restrict__ wl_g,
    const float* __restrict__ fc1_w, const float* __restrict__ fc1_b,
    const float* __restrict__ scale1, const float* __restrict__ shift1,
    const float* __restrict__ conv_w, const float* __restrict__ conv_b,
    const float* __restrict__ scale2, const float* __restrict__ shift2,
    const float* __restrict__ fc2_w, const float* __restrict__ fc2_b,
    const float* __restrict__ gl_scale,
    const float* __restrict__ ln_w, const float* __restrict__ ln_b,
    __hip_bfloat16* __restrict__ ybf) {
  __shared__ float sl[RB_*SROW_];
  __shared__ float cw[192], cb[64];
  __shared__ float sc1[64], sh1[64], sc2[64], sh2[64];
  int t = threadIdx.x;
  int row0 = blockIdx.x*RB_;
  if (t<64) { sc1[t]=scale1[t]; sh1[t]=shift1[t]; sc2[t]=scale2[t]; sh2[t]=shift2[t]; cb[t]=conv_b[t]; }
  if (t>=64 && t<256) cw[t-64]=conv_w[t-64];
  __syncthreads();
  for (int idx=t; idx<RB_*520; idx+=256) {
    int rr = idx/520, cc = idx - rr*520;
    sl[rr*SROW_+cc] = s_raw[(size_t)(row0+rr)*SROW_+cc];
  }
  __syncthreads();
  float glv = gl_scale[0];
  for (int idx=t; idx<RB_*64; idx+=256) {
    int rr = idx>>6, n = idx&63;
    float wlv = wl_g[(size_t)row0*64 + idx];
    float h[32];
    {
      float sp[16];
      #pragma unroll
      for (int p=0;p<16;++p) sp[p] = sl[rr*SROW_ + n*8 + p];
      float scn=sc1[n], shn=sh1[n];
      #pragma unroll
      for (int hid=0;hid<32;++hid) {
        float acc=fc1_b[hid];
        #pragma unroll
        for (int p=0;p<16;++p) acc=fmaf(sp[p], fc1_w[hid*16+p], acc);
        h[hid]=fmaf(gelu_f(acc), scn, shn);
      }
    }
    {
      float w0=cw[n*3], wm=cw[n*3+1], wpp=cw[n*3+2], cbn=cb[n];
      float sc2n=sc2[n], sh2n=sh2[n];
      float prev=0.f;
      #pragma unroll
      for (int k2=0;k2<32;++k2) {
        float cur = h[k2];
        float cv = cbn;
        cv = fmaf(prev, w0, cv);
        cv = fmaf(cur, wm, cv);
        if (k2<31) cv = fmaf(h[k2+1], wpp, cv);
        h[k2] = fmaf(gelu_f(cv), sc2n, sh2n);
        prev = cur;
      }
    }
    float yv[16];
    #pragma unroll
    for (int p=0;p<16;++p) {
      float acc=fc2_b[p];
      #pragma unroll
      for (int hid=0;hid<32;++hid) acc=fmaf(h[hid], fc2_w[p*32+hid], acc);
      yv[p]=acc;
    }
    float smul = 3.0f + glv*wlv;
    float mu=0.f;
    #pragma unroll
    for (int p=0;p<16;++p) {
      yv[p]=fmaf(sl[rr*SROW_ + n*8 + p], smul, yv[p]);
      mu+=yv[p];
    }
    mu *= (1.0f/16.0f);
    float var=0.f;
    #pragma unroll
    for (int p=0;p<16;++p){ float d=yv[p]-mu; var=fmaf(d,d,var); }
    var *= (1.0f/16.0f);
    float rs = rsqrtf(var + EPS_);
    unsigned int wds[8];
    #pragma unroll
    for (int j=0;j<8;++j) {
      unsigned int lo = bf16bits(fmaf((yv[2*j]-mu)*rs,   ln_w[2*j],   ln_b[2*j]));
      unsigned int hi = bf16bits(fmaf((yv[2*j+1]-mu)*rs, ln_w[2*j+1], ln_b[2*j+1]));
      wds[j] = lo | (hi<<16);
    }
    size_t ybase = (size_t)(row0+rr)*1024 + n*16;
    uint4* dst = (uint4*)&ybf[ybase];
    dst[0] = make_uint4(wds[0],wds[1],wds[2],wds[3]);
    dst[1] = make_uint4(wds[4],wds[5],wds[6],wds[7]);
  }
}

// ---------- K5a_v3: fc2 dot over pre-gelu'd g2 (no transcendentals) ----------
// yv[p] = fc2_b[p] + sh2*fc2cs[p] + sc2 * sum_k g2[k]*fc2T[k][p]
__global__ __launch_bounds__(256) void k5a_v3(
    const float* __restrict__ s_raw, const float* __restrict__ wl_g,
    const __hip_bfloat16* __restrict__ g2p,
    const float* __restrict__ scale2, const float* __restrict__ shift2,
    const float* __restrict__ fc2T, const float* __restrict__ fc2cs,
    const float* __restrict__ fc2_b,
    const float* __restrict__ gl_scale,
    const float* __restrict__ ln_w, const float* __restrict__ ln_b,
    __hip_bfloat16* __restrict__ ybf) {
  __shared__ float sl[RB_*SROW_];
  __shared__ float sc2[64], sh2[64];
  int t = threadIdx.x;
  int row0 = blockIdx.x*RB_;
  if (t < 64) { sc2[t]=scale2[t]; sh2[t]=shift2[t]; }
  __syncthreads();
  for (int idx=t; idx<RB_*520; idx+=256) {
    int rr = idx/520, cc = idx - rr*520;
    sl[rr*SROW_+cc] = s_raw[(size_t)(row0+rr)*SROW_+cc];
  }
  __syncthreads();
  float glv = gl_scale[0];
  for (int idx=t; idx<RB_*64; idx+=256) {
    int rr = idx>>6, n = idx&63;
    float wlv = wl_g[(size_t)row0*64 + idx];
    const uint4* crb = (const uint4*)&g2p[((size_t)(row0+rr)*64 + n)*32];
    uint4 u0=crb[0], u1=crb[1], u2=crb[2], u3=crb[3];
    unsigned uw[16] = {u0.x,u0.y,u0.z,u0.w, u1.x,u1.y,u1.z,u1.w,
                       u2.x,u2.y,u2.z,u2.w, u3.x,u3.y,u3.z,u3.w};
    float sc2n = sc2[n], sh2n = sh2[n];
    float dot[16];
    #pragma unroll
    for (int p=0;p<16;++p) dot[p] = 0.f;
    #pragma unroll
    for (int j=0;j<16;++j) {
      unsigned u = uw[j];
      float g0 = __uint_as_float(u<<16);
      float g1 = __uint_as_float(u & 0xffff0000u);
      const float* w0r = &fc2T[(2*j)*16];
      const float* w1r = &fc2T[(2*j+1)*16];
      #pragma unroll
      for (int p=0;p<16;++p)
        dot[p] = fmaf(g0, w0r[p], fmaf(g1, w1r[p], dot[p]));
    }
    float smul = 3.0f + glv*wlv;
    float yv[16]; float mu=0.f;
    #pragma unroll
    for (int p=0;p<16;++p) {
      float v = fmaf(sc2n, dot[p], fmaf(sh2n, fc2cs[p], fc2_b[p]));
      v = fmaf(sl[rr*SROW_ + n*8 + p], smul, v);
      yv[p] = v; mu += v;
    }
    mu *= (1.0f/16.0f);
    float var=0.f;
    #pragma unroll
    for (int p=0;p<16;++p){ float d=yv[p]-mu; var=fmaf(d,d,var); }
    var *= (1.0f/16.0f);
    float rs = rsqrtf(var + EPS_);
    unsigned int wds[8];
    #pragma unroll
    for (int j=0;j<8;++j) {
      unsigned int lo = bf16bits(fmaf((yv[2*j]-mu)*rs,   ln_w[2*j],   ln_b[2*j]));
      unsigned int hi = bf16bits(fmaf((yv[2*j+1]-mu)*rs, ln_w[2*j+1], ln_b[2*j+1]));
      wds[j] = lo | (hi<<16);
    }
    size_t ybase = (size_t)(row0+rr)*1024 + n*16;
    uint4* dst = (uint4*)&ybf[ybase];
    dst[0] = make_uint4(wds[0],wds[1],wds[2],wds[3]);
    dst[1] = make_uint4(wds[4],wds[5],wds[6],wds[7]);
  }
}

// ---------- K5b: bf16 MFMA GEMM, double-buffered, merged 24-step K-loop ----------
__global__ __launch_bounds__(256) void k5b_gemm(
    const __hip_bfloat16* __restrict__ ybf, const __hip_bfloat16* __restrict__ tbf,
    const __hip_bfloat16* __restrict__ Wsf, const __hip_bfloat16* __restrict__ Wtf,
    const float* __restrict__ rowpar, const float* __restrict__ rev_b,
    const float* __restrict__ biasc, const float* __restrict__ colsumT,
    float* __restrict__ out) {
  __shared__ __align__(16) __hip_bfloat16 As[2*64*72];
  __shared__ __align__(16) __hip_bfloat16 Bs[2*96*72];
  __shared__ float rp[256];
  __shared__ float rbl[64];
  __shared__ int   obase[64];
  __shared__ float bcl[96], csl[96];
  int tid = threadIdx.x;
  int row0 = blockIdx.x*64;
  rp[tid] = rowpar[(size_t)row0*4 + tid];
  if (tid < 64) {
    int row = row0 + tid; int b = row/C_; int c = row - b*C_;
    rbl[tid] = rev_b[c]; obase[tid] = b*PRED_*C_ + c;
  }
  if (tid >= 128 && tid < 224) { bcl[tid-128]=biasc[tid-128]; csl[tid-128]=colsumT[tid-128]; }
  int lane = tid & 63, w = tid >> 6;
  int fr = lane & 15, fg = lane >> 4;
  int ra0 = tid>>3,       ca0 = tid&7;
  int ra1 = (tid+256)>>3, ca1 = (tid+256)&7;
  int rb0 = ra0, cb0_ = ca0;
  int rb1 = ra1, cb1_ = ca1;
  int rb2 = (tid+512)>>3, cb2_ = (tid+512)&7;
  f32x4 acc[6];
  #pragma unroll
  for (int n=0;n<6;++n) acc[n] = (f32x4){0.f,0.f,0.f,0.f};

  uint4 ar[2], br[3];
  auto LOAD = [&](int ks){
    if (ks < 8) {
      int kofs = ks*64;
      ar[0] = *(const uint4*)&tbf[(size_t)(row0+ra0)*512 + kofs + ca0*8];
      ar[1] = *(const uint4*)&tbf[(size_t)(row0+ra1)*512 + kofs + ca1*8];
      br[0] = *(const uint4*)&Wtf[(size_t)rb0*512 + kofs + cb0_*8];
      br[1] = *(const uint4*)&Wtf[(size_t)rb1*512 + kofs + cb1_*8];
      br[2] = *(const uint4*)&Wtf[(size_t)rb2*512 + kofs + cb2_*8];
    } else {
      int kofs = (ks-8)*64;
      ar[0] = *(const uint4*)&ybf[(size_t)(row0+ra0)*1024 + kofs + ca0*8];
      ar[1] = *(const uint4*)&ybf[(size_t)(row0+ra1)*1024 + kofs + ca1*8];
      br[0] = *(const uint4*)&Wsf[(size_t)rb0*1024 + kofs + cb0_*8];
      br[1] = *(const uint4*)&Wsf[(size_t)rb1*1024 + kofs + cb1_*8];
      br[2] = *(const uint4*)&Wsf[(size_t)rb2*1024 + kofs + cb2_*8];
    }
  };

  LOAD(0);
  int cur = 0;
  for (int ks=0; ks<24; ++ks) {
    __hip_bfloat16* Ab = &As[cur*64*72];
    __hip_bfloat16* Bb = &Bs[cur*96*72];
    *(uint4*)&Ab[ra0*72 + ca0*8] = ar[0];
    *(uint4*)&Ab[ra1*72 + ca1*8] = ar[1];
    *(uint4*)&Bb[rb0*72 + cb0_*8] = br[0];
    *(uint4*)&Bb[rb1*72 + cb1_*8] = br[1];
    *(uint4*)&Bb[rb2*72 + cb2_*8] = br[2];
    __syncthreads();
    if (ks < 23) LOAD(ks+1);
    #pragma unroll
    for (int ksub=0; ksub<2; ++ksub) {
      bf16x8 av = *(bf16x8*)&Ab[(w*16+fr)*72 + ksub*32 + fg*8];
      #pragma unroll
      for (int n=0;n<6;++n) {
        bf16x8 bv = *(bf16x8*)&Bb[(n*16+fr)*72 + ksub*32 + fg*8];
        acc[n] = __builtin_amdgcn_mfma_f32_16x16x32_bf16(av, bv, acc[n], 0,0,0);
      }
    }
    cur ^= 1;
  }
  #pragma unroll
  for (int n=0;n<6;++n) {
    int col = n*16 + fr;
    float cs = csl[col], bc = bcl[col];
    #pragma unroll
    for (int reg=0;reg<4;++reg) {
      int rloc = w*16 + fg*4 + reg;
      float g = rp[rloc*4+1], meanv = rp[rloc*4+2], inva = rp[rloc*4+3];
      float val = acc[n][reg] + g*cs + bc;
      val = (val - rbl[rloc])*inva + meanv;
      out[(size_t)obase[rloc] + (size_t)col*C_] = val;
    }
  }
}

extern "C" void kernel_launch(void* const* d_in, const int* in_sizes, int n_in,
                              void* d_out, int out_size, void* d_ws, size_t ws_size,
                              hipStream_t stream) {
  const float* x      = (const float*)d_in[0];
  const float* rev_w  = (const float*)d_in[1];
  const float* rev_b  = (const float*)d_in[2];
  const float* fc1_w  = (const float*)d_in[3];
  const float* fc1_b  = (const float*)d_in[4];
  const float* bn1_w  = (const float*)d_in[5];
  const float* bn1_b  = (const float*)d_in[6];
  const float* conv_w = (const float*)d_in[7];
  const float* conv_b = (const float*)d_in[8];
  const float* bn2_w  = (const float*)d_in[9];
  const float* bn2_b  = (const float*)d_in[10];
  const float* fc2_w  = (const float*)d_in[11];
  const float* fc2_b  = (const float*)d_in[12];
  const float* m1_w   = (const float*)d_in[13];
  const float* m1_b   = (const float*)d_in[14];
  const float* m2_w   = (const float*)d_in[15];
  const float* m2_b   = (const float*)d_in[16];
  const float* gl     = (const float*)d_in[17];
  const float* ln_w   = (const float*)d_in[18];
  const float* ln_b   = (const float*)d_in[19];
  const float* seas_w = (const float*)d_in[20];
  const float* seas_b = (const float*)d_in[21];
  const float* tr_w   = (const float*)d_in[22];
  const float* tr_b   = (const float*)d_in[23];
  const float* fus_w  = (const float*)d_in[24];
  const float* fus_b  = (const float*)d_in[25];
  float* out = (float*)d_out;
  float* ws = (float*)d_ws;

  __hip_bfloat16* Wsf  = (__hip_bfloat16*)(ws);
  __hip_bfloat16* Wtf  = (__hip_bfloat16*)(ws + 49152);
  float* biasc   = ws + 73728;
  float* colsumT = ws + 73856;
  float* scale1  = ws + 73984;
  float* shift1  = ws + 74048;
  float* scale2  = ws + 74112;
  float* shift2  = ws + 74176;
  float* partials= ws + 74240;
  float* rowpar  = ws + 238592;
  float* s_raw   = ws + 320768;
  __hip_bfloat16* t_bf = (__hip_bfloat16*)(ws + 11168000);
  __hip_bfloat16* ybf  = (__hip_bfloat16*)(ws + 16427264);
  float* pooled  = ws + 26945792;
  float* wl_g    = ws + 28260608;
  __hip_bfloat16* crp  = (__hip_bfloat16*)(ws + 29575424);  // BC*2048 bf16
  float* fc2T    = ws + 50612480;   // 512
  float* fc2cs   = ws + 50612992;   // 16
  const size_t NEED = 50613056ull * 4ull;   // ~202.5 MB
  bool big = (ws_size >= NEED);

  hipLaunchKernelGGL(k0_fold,  dim3(576),  dim3(256), 0, stream, seas_w, tr_w, fus_w, Wsf, Wtf);
  if (big) {
    hipLaunchKernelGGL(k0b_bias, dim3(1), dim3(128), 0, stream, seas_b, tr_b, fus_w, fus_b, tr_w, fc2_w, biasc, colsumT, fc2T, fc2cs);
  } else {
    // small-ws: fc2T/fc2cs land nowhere safe; reuse partials tail (unused until k2)
    hipLaunchKernelGGL(k0b_bias, dim3(1), dim3(128), 0, stream, seas_b, tr_b, fus_w, fus_b, tr_w, fc2_w, biasc, colsumT, partials, partials+512);
  }
  hipLaunchKernelGGL(k1_revin_ema, dim3(BC_/32), dim3(256), 0, stream, x, rev_w, rev_b, s_raw, t_bf, rowpar, pooled);
  hipLaunchKernelGGL(k4_gate, dim3(BC_/64), dim3(256), 0, stream, pooled, m1_w, m1_b, m2_w, m2_b, wl_g);
  if (big) {
    hipLaunchKernelGGL(k2v2_bn1_cr, dim3(NBLK2_), dim3(256), 0, stream, s_raw, fc1_w, fc1_b, conv_w, partials, crp);
    hipLaunchKernelGGL(k_bnreduce, dim3(64), dim3(256), 0, stream, partials, NBLK2_, bn1_w, bn1_b, scale1, shift1);
    hipLaunchKernelGGL(k3v2_bn2stats, dim3(NBLK2_), dim3(256), 0, stream, crp, scale1, shift1, conv_w, conv_b, partials);
    hipLaunchKernelGGL(k_bnreduce, dim3(64), dim3(256), 0, stream, partials, NBLK2_, bn2_w, bn2_b, scale2, shift2);
    hipLaunchKernelGGL(k5a_v3, dim3(BC_/RB_), dim3(256), 0, stream,
      s_raw, wl_g, crp, scale2, shift2, fc2T, fc2cs, fc2_b, gl, ln_w, ln_b, ybf);
  } else {
    hipLaunchKernelGGL(k2_bn1stats, dim3(NBLK2_), dim3(256), 0, stream, s_raw, fc1_w, fc1_b, partials);
    hipLaunchKernelGGL(k_bnreduce, dim3(64), dim3(256), 0, stream, partials, NBLK2_, bn1_w, bn1_b, scale1, shift1);
    hipLaunchKernelGGL(k3_bn2stats, dim3(NBLK2_), dim3(256), 0, stream, s_raw, fc1_w, fc1_b, scale1, shift1, conv_w, conv_b, partials);
    hipLaunchKernelGGL(k_bnreduce, dim3(64), dim3(256), 0, stream, partials, NBLK2_, bn2_w, bn2_b, scale2, shift2);
    hipLaunchKernelGGL(k5a_pipeline, dim3(BC_/RB_), dim3(256), 0, stream,
      s_raw, wl_g, fc1_w, fc1_b, scale1, shift1, conv_w, conv_b,
      scale2, shift2, fc2_w, fc2_b, gl, ln_w, ln_b, ybf);
  }
  hipLaunchKernelGGL(k5b_gemm, dim3(BC_/64), dim3(256), 0, stream,
    ybf, t_bf, Wsf, Wtf, rowpar, rev_b, biasc, colsumT, out);
}

// Round 10
// 423.344 us; speedup vs baseline: 1.1374x; 1.1374x over previous
//
#include <hip/hip_runtime.h>
#include <hip/hip_bf16.h>
#include <math.h>

#define B_    64
#define L_    512
#define C_    321
#define PRED_ 96
#define N_    64
#define HID_  32
#define BC_   (B_*C_)   // 20544
#define SROW_ 528
#define EPS_  1e-5f
#define ALPHA_ 0.2f
#define GR_   16
#define RB_   8
#define NBLK2_ (BC_/GR_) // 1284
#define D64_  6.2771017353866808e-7f   // 0.8^64
#define STW_  548   // f32 stage stride: 548&31==4 -> <=4-way fill conflicts
#define UTW_  260   // uint stage stride for t (260&31==4)

typedef __attribute__((ext_vector_type(8))) short bf16x8;
typedef __attribute__((ext_vector_type(4))) float f32x4;

// Fast gelu: A&S 7.1.26 erf approx, |eps|<=1.5e-7, branch-free.
__device__ __forceinline__ float gelu_f(float x){
  float ax = fabsf(x);
  float z  = ax * 0.70710678118654752440f;
  float t  = __builtin_amdgcn_rcpf(fmaf(0.3275911f, z, 1.0f));
  float poly = fmaf(fmaf(fmaf(fmaf(1.061405429f, t, -1.453152027f),
                   t, 1.421413741f), t, -0.284496736f), t, 0.254829592f) * t;
  float e  = __expf(-z*z);
  float erfp = fmaf(-poly, e, 1.0f);
  return fmaf(0.5f*ax, erfp, 0.5f*x);
}
__device__ __forceinline__ unsigned short bf16bits(float x){
  __hip_bfloat16 h = __float2bfloat16(x);
  return *(unsigned short*)&h;
}

// ---------- K0: fold seas/tr matmuls through fus; bf16 col-major [j][k] ----------
__global__ __launch_bounds__(256) void k0_fold(
    const float* __restrict__ seas_w, const float* __restrict__ tr_w,
    const float* __restrict__ fus_w,
    __hip_bfloat16* __restrict__ Wsf, __hip_bfloat16* __restrict__ Wtf) {
  int idx = blockIdx.x*256 + threadIdx.x;
  if (idx >= 96*1536) return;
  int j = idx / 1536, k = idx - j*1536;
  float acc = 0.f;
  if (k < 1024) {
    for (int i=0;i<96;++i) acc = fmaf(fus_w[j*192+i], seas_w[i*1024+k], acc);
    Wsf[(size_t)j*1024 + k] = __float2bfloat16(acc);
  } else {
    int l = k - 1024;
    for (int i=0;i<96;++i) acc = fmaf(fus_w[j*192+96+i], tr_w[i*512+l], acc);
    Wtf[(size_t)j*512 + l] = __float2bfloat16(acc);
  }
}

// ---------- K0b ----------
__global__ void k0b_bias(
    const float* __restrict__ seas_b, const float* __restrict__ tr_b,
    const float* __restrict__ fus_w, const float* __restrict__ fus_b,
    const float* __restrict__ tr_w,
    float* __restrict__ biasc, float* __restrict__ colsumT) {
  __shared__ float rowsum[96];
  int t = threadIdx.x;
  if (t < 96) {
    float s = 0.f;
    for (int l=0;l<512;++l) s += tr_w[t*512+l];
    rowsum[t] = s;
  }
  __syncthreads();
  if (t < 96) {
    float acc = fus_b[t], cs = 0.f;
    for (int i=0;i<96;++i) {
      acc = fmaf(fus_w[t*192+i],    seas_b[i], acc);
      acc = fmaf(fus_w[t*192+96+i], tr_b[i],   acc);
      cs  = fmaf(fus_w[t*192+96+i], rowsum[i], cs);
    }
    biasc[t] = acc; colsumT[t] = cs;
  }
}

// ---------- K1: RevIN + EMA, single x read, LDS-staged COALESCED stores ----------
// 8 chunks x 32 rows; s-tile (f32) and t-tile (packed bf16) staged in LDS
// with stride ≡ 4 (mod 32), then stored as coalesced float4/uint4 rows.
__global__ __launch_bounds__(256) void k1_revin_ema(
    const float* __restrict__ x, const float* __restrict__ rev_w, const float* __restrict__ rev_b,
    float* __restrict__ s_raw, __hip_bfloat16* __restrict__ t_bf, float* __restrict__ rowpar,
    float* __restrict__ pooled) {
  __shared__ float lf[8][32];
  __shared__ float psum[8][32], psq[8][32];
  __shared__ float fs[8][32];             // per-chunk sums8[0]
  __shared__ float st[32*STW_];           // 70KB stage (reused as uint for t)
  int tid = threadIdx.x;
  int q = tid >> 5, r = tid & 31;
  int row0 = blockIdx.x*32;
  int row = row0 + r;
  int b = row / C_, c = row - b*C_;
  const float* xp = x + (size_t)b*L_*C_ + c;
  int l0 = q*64;
  float sreg[64];
  // pass A: load x once, stats + local scan (loc kept in sreg)
  float loc = 0.f, sum = 0.f, sq = 0.f;
  #pragma unroll
  for (int i=0;i<64;++i) {
    float v = xp[(size_t)(l0+i)*C_];
    sum += v; sq = fmaf(v,v,sq);
    loc = (q==0 && i==0) ? v : fmaf(ALPHA_, v, 0.8f*loc);
    sreg[i] = loc;
  }
  lf[q][r] = loc; psum[q][r] = sum; psq[q][r] = sq;
  __syncthreads();
  float cin = 0.f;
  for (int j=0;j<q;++j) cin = fmaf(D64_, cin, lf[j][r]);
  float S=0.f, Q=0.f;
  #pragma unroll
  for (int qq=0;qq<8;++qq){ S += psum[qq][r]; Q += psq[qq][r]; }
  float mean = S*(1.0f/512.0f);
  float var  = (Q - S*S*(1.0f/512.0f))*(1.0f/511.0f);
  var = fmaxf(var, 0.f);
  float stdv = sqrtf(var) + EPS_;
  float rwc = rev_w[c];
  float a = rwc / stdv;
  if (q==0) {
    float rbc = rev_b[c];
    float g = rbc - mean*a;
    float inva = stdv / rwc;
    ((float4*)rowpar)[row] = make_float4(a, g, mean, inva);
  }
  // fill s-stage: s = 4*(loc - prev) - f*cin (exact reconstruction), scaled by a
  float prev = 0.f, f = 1.f, slast = 0.f;
  float sums8[8];
  #pragma unroll
  for (int j=0;j<8;++j) sums8[j] = 0.f;
  #pragma unroll
  for (int i=0;i<64;++i) {
    float lc = sreg[i];
    f *= 0.8f;
    float s = (q==0 && i==0) ? 0.f : fmaf(4.f, lc - prev, -f*cin);
    prev = lc;
    float sv = s * a;
    st[r*STW_ + q*64 + i] = sv;
    sums8[i>>3] += sv;
    slast = sv;
  }
  fs[q][r] = sums8[0];
  if (q==7) {
    #pragma unroll
    for (int k=0;k<8;++k) st[r*STW_ + 512 + k] = slast;
  }
  __syncthreads();
  // coalesced s_raw store: 32 rows x 130 float4-groups
  for (int idx=tid; idx<32*130; idx+=256) {
    int rr = idx/130, g = idx - rr*130;
    float4 v = *(float4*)&st[rr*STW_ + g*4];
    *(float4*)&s_raw[(size_t)(row0+rr)*SROW_ + g*4] = v;
  }
  // pooled (patch j of chunk q = sums8[j] + next-8 sum)
  {
    float nf = (q < 7) ? fs[q+1][r] : 8.0f*slast;
    #pragma unroll
    for (int j=0;j<7;++j)
      pooled[(size_t)row*64 + q*8 + j] = (sums8[j] + sums8[j+1])*(1.0f/16.0f);
    pooled[(size_t)row*64 + q*8 + 7] = (sums8[7] + nf)*(1.0f/16.0f);
  }
  __syncthreads();
  // fill t-stage (packed bf16 pairs), reusing st as uint
  unsigned* tb = (unsigned*)st;
  {
    float f2 = 1.f; unsigned lo = 0;
    #pragma unroll
    for (int i=0;i<64;++i) {
      f2 *= 0.8f;
      float tt = fmaf(f2, cin, sreg[i]) * a;
      unsigned hb = bf16bits(tt);
      if ((i&1)==0) lo = hb;
      else tb[r*UTW_ + q*32 + (i>>1)] = lo | (hb<<16);
    }
  }
  __syncthreads();
  // coalesced t_bf store: 32 rows x 64 uint4-groups (256 uints/row)
  for (int idx=tid; idx<32*64; idx+=256) {
    int rr = idx>>6, g = idx&63;
    uint4 v = *(uint4*)&tb[rr*UTW_ + g*4];
    *(uint4*)&t_bf[(size_t)(row0+rr)*512 + g*8] = v;
  }
}

// ---------- K4: gate MLP ----------
__global__ __launch_bounds__(256) void k4_gate(
    const float* __restrict__ pooled,
    const float* __restrict__ m1_w, const float* __restrict__ m1_b,
    const float* __restrict__ m2_w, const float* __restrict__ m2_b,
    float* __restrict__ wl_g) {
  __shared__ float pl[64][65];
  __shared__ float h1[64][129];
  int t = threadIdx.x;
  int row0 = blockIdx.x*64;
  for (int idx=t; idx<4096; idx+=256)
    pl[idx>>6][idx&63] = pooled[(size_t)row0*64 + idx];
  __syncthreads();
  int w = t>>6, l = t&63;
  for (int ii=0; ii<32; ++ii) {
    int i = w*32 + ii;
    float acc = m1_b[i];
    #pragma unroll
    for (int k=0;k<64;++k) acc = fmaf(pl[l][k], m1_w[i*64+k], acc);
    h1[l][i] = gelu_f(acc);
  }
  __syncthreads();
  for (int jj=0; jj<16; ++jj) {
    int n = w*16 + jj;
    float acc = m2_b[n];
    #pragma unroll
    for (int k=0;k<128;++k) acc = fmaf(h1[l][k], m2_w[n*128+k], acc);
    wl_g[(size_t)(row0+l)*64 + n] = 1.0f/(1.0f + __expf(-acc));
  }
}

// ---------- K2 (fallback): BN1 statistics ----------
__global__ __launch_bounds__(256) void k2_bn1stats(
    const float* __restrict__ s_raw,
    const float* __restrict__ fc1_w, const float* __restrict__ fc1_b,
    float* __restrict__ partials) {
  __shared__ float sl[GR_*SROW_];
  __shared__ float red[2][GR_*64];
  int t = threadIdx.x;
  int row0 = blockIdx.x*GR_;
  for (int idx=t; idx<GR_*520; idx+=256) {
    int rr = idx/520, cc = idx - rr*520;
    sl[rr*SROW_+cc] = s_raw[(size_t)(row0+rr)*SROW_+cc];
  }
  __syncthreads();
  int lr = t >> 4, ng = t & 15;
  for (int q=0;q<4;++q) {
    int n = ng + 16*q;
    float sp[16];
    #pragma unroll
    for (int p=0;p<16;++p) sp[p] = sl[lr*SROW_ + n*8 + p];
    float s1=0.f, s2=0.f;
    #pragma unroll
    for (int hid=0; hid<32; ++hid) {
      float acc = fc1_b[hid];
      #pragma unroll
      for (int p=0;p<16;++p) acc = fmaf(sp[p], fc1_w[hid*16+p], acc);
      float gv = gelu_f(acc);
      s1 += gv; s2 = fmaf(gv,gv,s2);
    }
    red[0][lr*64+n] = s1;
    red[1][lr*64+n] = s2;
  }
  __syncthreads();
  if (t < 64) {
    float S1=0.f, S2=0.f;
    for (int lr2=0; lr2<GR_; ++lr2) { S1 += red[0][lr2*64+t]; S2 += red[1][lr2*64+t]; }
    partials[((size_t)blockIdx.x*64+t)*2+0] = S1;
    partials[((size_t)blockIdx.x*64+t)*2+1] = S2;
  }
}

// ---------- K2v2: BN1 stats + materialize cr = conv3(gelu(fc1(s))) in bf16 ----------
__global__ __launch_bounds__(256) void k2v2_bn1_cr(
    const float* __restrict__ s_raw,
    const float* __restrict__ fc1_w, const float* __restrict__ fc1_b,
    const float* __restrict__ conv_w,
    float* __restrict__ partials, __hip_bfloat16* __restrict__ crp) {
  __shared__ float sl[GR_*SROW_];
  __shared__ float cw[192];
  __shared__ float red[2][GR_*64];
  int t = threadIdx.x;
  int row0 = blockIdx.x*GR_;
  if (t < 192) cw[t] = conv_w[t];
  for (int idx=t; idx<GR_*520; idx+=256) {
    int rr = idx/520, cc = idx - rr*520;
    sl[rr*SROW_+cc] = s_raw[(size_t)(row0+rr)*SROW_+cc];
  }
  __syncthreads();
  int lr = t >> 4, ng = t & 15;
  for (int q=0;q<4;++q) {
    int n = ng + 16*q;
    float sp[16];
    #pragma unroll
    for (int p=0;p<16;++p) sp[p] = sl[lr*SROW_ + n*8 + p];
    float w0=cw[n*3], wm=cw[n*3+1], wp=cw[n*3+2];
    float s1=0.f, s2=0.f;
    auto gf = [&](int k)->float {
      float acc = fc1_b[k];
      #pragma unroll
      for (int p=0;p<16;++p) acc = fmaf(sp[p], fc1_w[k*16+p], acc);
      float g = gelu_f(acc);
      s1 += g; s2 = fmaf(g,g,s2);
      return g;
    };
    float gm = 0.f, gc = gf(0), gp = gf(1);
    unsigned wds[16]; unsigned crlo = 0;
    #pragma unroll
    for (int k=0;k<32;++k) {
      float cr = fmaf(gm, w0, fmaf(gc, wm, (k<31) ? gp*wp : 0.f));
      unsigned hb = bf16bits(cr);
      if ((k&1)==0) crlo = hb; else wds[k>>1] = crlo | (hb<<16);
      gm = gc; gc = gp;
      gp = (k+2<32) ? gf(k+2) : 0.f;
    }
    uint4* dst = (uint4*)&crp[((size_t)(row0+lr)*64 + n)*32];
    dst[0] = make_uint4(wds[0],wds[1],wds[2],wds[3]);
    dst[1] = make_uint4(wds[4],wds[5],wds[6],wds[7]);
    dst[2] = make_uint4(wds[8],wds[9],wds[10],wds[11]);
    dst[3] = make_uint4(wds[12],wds[13],wds[14],wds[15]);
    red[0][lr*64+n] = s1;
    red[1][lr*64+n] = s2;
  }
  __syncthreads();
  if (t < 64) {
    float S1=0.f, S2=0.f;
    for (int lr2=0; lr2<GR_; ++lr2) { S1 += red[0][lr2*64+t]; S2 += red[1][lr2*64+t]; }
    partials[((size_t)blockIdx.x*64+t)*2+0] = S1;
    partials[((size_t)blockIdx.x*64+t)*2+1] = S2;
  }
}

// ---------- bn reduce ----------
__global__ __launch_bounds__(256) void k_bnreduce(
    const float* __restrict__ partials, int nblk,
    const float* __restrict__ bnw, const float* __restrict__ bnb,
    float* __restrict__ scale, float* __restrict__ shift) {
  __shared__ float red[2][256];
  int n = blockIdx.x, t = threadIdx.x;
  float s1=0.f, s2=0.f;
  for (int i=t; i<nblk; i+=256) {
    s1 += partials[((size_t)i*64+n)*2+0];
    s2 += partials[((size_t)i*64+n)*2+1];
  }
  red[0][t]=s1; red[1][t]=s2;
  __syncthreads();
  for (int off=128; off>0; off>>=1) {
    if (t<off) { red[0][t]+=red[0][t+off]; red[1][t]+=red[1][t+off]; }
    __syncthreads();
  }
  if (t==0) {
    const float count = (float)BC_ * 32.0f;
    float mu = red[0][0]/count;
    float var = red[1][0]/count - mu*mu;
    float sc = rsqrtf(var + EPS_) * bnw[n];
    scale[n] = sc;
    shift[n] = bnb[n] - mu*sc;
  }
}

// ---------- K3 (fallback): BN2 statistics ----------
__global__ __launch_bounds__(256) void k3_bn2stats(
    const float* __restrict__ s_raw,
    const float* __restrict__ fc1_w, const float* __restrict__ fc1_b,
    const float* __restrict__ scale1, const float* __restrict__ shift1,
    const float* __restrict__ conv_w, const float* __restrict__ conv_b,
    float* __restrict__ partials) {
  __shared__ float sl[GR_*SROW_];
  __shared__ float sc1[64], sh1[64], cw[192], cb[64];
  __shared__ float red[2][GR_*64];
  int t = threadIdx.x;
  int row0 = blockIdx.x*GR_;
  if (t < 64) { sc1[t]=scale1[t]; sh1[t]=shift1[t]; cb[t]=conv_b[t]; }
  if (t >= 64 && t < 256) cw[t-64] = conv_w[t-64];
  __syncthreads();
  for (int idx=t; idx<GR_*520; idx+=256) {
    int rr = idx/520, cc = idx - rr*520;
    sl[rr*SROW_+cc] = s_raw[(size_t)(row0+rr)*SROW_+cc];
  }
  __syncthreads();
  int lr = t >> 4, ng = t & 15;
  for (int q=0;q<4;++q) {
    int n = ng + 16*q;
    float sp[16];
    #pragma unroll
    for (int p=0;p<16;++p) sp[p] = sl[lr*SROW_ + n*8 + p];
    float scn = sc1[n], shn = sh1[n];
    float h[32];
    #pragma unroll
    for (int hid=0; hid<32; ++hid) {
      float acc = fc1_b[hid];
      #pragma unroll
      for (int p=0;p<16;++p) acc = fmaf(sp[p], fc1_w[hid*16+p], acc);
      h[hid] = fmaf(gelu_f(acc), scn, shn);
    }
    float w0=cw[n*3], wm=cw[n*3+1], wpp=cw[n*3+2], cbn=cb[n];
    float s1=0.f, s2=0.f, prev=0.f;
    #pragma unroll
    for (int k2=0;k2<32;++k2) {
      float cur = h[k2];
      float cv = cbn;
      cv = fmaf(prev, w0, cv);
      cv = fmaf(cur, wm, cv);
      if (k2<31) cv = fmaf(h[k2+1], wpp, cv);
      float gv = gelu_f(cv);
      s1 += gv; s2 = fmaf(gv,gv,s2);
      prev = cur;
    }
    red[0][lr*64+n]=s1; red[1][lr*64+n]=s2;
  }
  __syncthreads();
  if (t < 64) {
    float S1=0.f, S2=0.f;
    for (int lr2=0; lr2<GR_; ++lr2) { S1 += red[0][lr2*64+t]; S2 += red[1][lr2*64+t]; }
    partials[((size_t)blockIdx.x*64+t)*2+0] = S1;
    partials[((size_t)blockIdx.x*64+t)*2+1] = S2;
  }
}

// ---------- K3v2: BN2 stats from materialized cr (read-only) ----------
__global__ __launch_bounds__(256) void k3v2_bn2stats(
    const __hip_bfloat16* __restrict__ crp,
    const float* __restrict__ scale1, const float* __restrict__ shift1,
    const float* __restrict__ conv_w, const float* __restrict__ conv_b,
    float* __restrict__ partials) {
  __shared__ float sc1[64], sh0l[64], shml[64], sh31l[64];
  __shared__ float red[2][GR_*64];
  int t = threadIdx.x;
  int row0 = blockIdx.x*GR_;
  if (t < 64) {
    float w0=conv_w[t*3], wm=conv_w[t*3+1], wp=conv_w[t*3+2];
    float s1v=shift1[t], cbv=conv_b[t];
    sc1[t]  = scale1[t];
    sh0l[t] = fmaf(s1v, wm+wp, cbv);
    shml[t] = fmaf(s1v, w0+wm+wp, cbv);
    sh31l[t]= fmaf(s1v, w0+wm, cbv);
  }
  __syncthreads();
  int lr = t >> 4, ng = t & 15;
  for (int q=0;q<4;++q) {
    int n = ng + 16*q;
    const uint4* crb = (const uint4*)&crp[((size_t)(row0+lr)*64 + n)*32];
    uint4 u0=crb[0], u1=crb[1], u2=crb[2], u3=crb[3];
    unsigned uw[16] = {u0.x,u0.y,u0.z,u0.w, u1.x,u1.y,u1.z,u1.w,
                       u2.x,u2.y,u2.z,u2.w, u3.x,u3.y,u3.z,u3.w};
    float sc1n = sc1[n];
    float shm = shml[n];
    float s1=0.f, s2=0.f;
    #pragma unroll
    for (int j=0;j<16;++j) {
      unsigned u = uw[j];
      float c0 = __uint_as_float(u<<16);
      float c1 = __uint_as_float(u & 0xffff0000u);
      float sh_0 = (j==0)  ? sh0l[n]  : shm;
      float sh_1 = (j==15) ? sh31l[n] : shm;
      float g0 = gelu_f(fmaf(c0, sc1n, sh_0));
      float g1 = gelu_f(fmaf(c1, sc1n, sh_1));
      s1 += g0 + g1;
      s2 = fmaf(g0,g0, fmaf(g1,g1, s2));
    }
    red[0][lr*64+n]=s1; red[1][lr*64+n]=s2;
  }
  __syncthreads();
  if (t < 64) {
    float S1=0.f, S2=0.f;
    for (int lr2=0; lr2<GR_; ++lr2) { S1 += red[0][lr2*64+t]; S2 += red[1][lr2*64+t]; }
    partials[((size_t)blockIdx.x*64+t)*2+0] = S1;
    partials[((size_t)blockIdx.x*64+t)*2+1] = S2;
  }
}

// ---------- K5a (fallback): full per-row pipeline ----------
__global__ __launch_bounds__(256) void k5a_pipeline(
    const float* __restrict__ s_raw, const float* __restrict__ wl_g,
    const float* __restrict__ fc1_w, const float* __restrict__ fc1_b,
    const float* __restrict__ scale1, const float* __restrict__ shift1,
    const float* __restrict__ conv_w, const float* __restrict__ conv_b,
    const float* __restrict__ scale2, const float* __restrict__ shift2,
    const float* __restrict__ fc2_w, const float* __restrict__ fc2_b,
    const float* __restrict__ gl_scale,
    const float* __restrict__ ln_w, const float* __restrict__ ln_b,
    __hip_bfloat16* __restrict__ ybf) {
  __shared__ float sl[RB_*SROW_];
  __shared__ float cw[192], cb[64];
  __shared__ float sc1[64], sh1[64], sc2[64], sh2[64];
  int t = threadIdx.x;
  int row0 = blockIdx.x*RB_;
  if (t<64) { sc1[t]=scale1[t]; sh1[t]=shift1[t]; sc2[t]=scale2[t]; sh2[t]=shift2[t]; cb[t]=conv_b[t]; }
  if (t>=64 && t<256) cw[t-64]=conv_w[t-64];
  __syncthreads();
  for (int idx=t; idx<RB_*520; idx+=256) {
    int rr = idx/520, cc = idx - rr*520;
    sl[rr*SROW_+cc] = s_raw[(size_t)(row0+rr)*SROW_+cc];
  }
  __syncthreads();
  float glv = gl_scale[0];
  for (int idx=t; idx<RB_*64; idx+=256) {
    int rr = idx>>6, n = idx&63;
    float wlv = wl_g[(size_t)row0*64 + idx];
    float h[32];
    {
      float sp[16];
      #pragma unroll
      for (int p=0;p<16;++p) sp[p] = sl[rr*SROW_ + n*8 + p];
      float scn=sc1[n], shn=sh1[n];
      #pragma unroll
      for (int hid=0;hid<32;++hid) {
        float acc=fc1_b[hid];
        #pragma unroll
        for (int p=0;p<16;++p) acc=fmaf(sp[p], fc1_w[hid*16+p], acc);
        h[hid]=fmaf(gelu_f(acc), scn, shn);
      }
    }
    {
      float w0=cw[n*3], wm=cw[n*3+1], wpp=cw[n*3+2], cbn=cb[n];
      float sc2n=sc2[n], sh2n=sh2[n];
      float prev=0.f;
      #pragma unroll
      for (int k2=0;k2<32;++k2) {
        float cur = h[k2];
        float cv = cbn;
        cv = fmaf(prev, w0, cv);
        cv = fmaf(cur, wm, cv);
        if (k2<31) cv = fmaf(h[k2+1], wpp, cv);
        h[k2] = fmaf(gelu_f(cv), sc2n, sh2n);
        prev = cur;
      }
    }
    float yv[16];
    #pragma unroll
    for (int p=0;p<16;++p) {
      float acc=fc2_b[p];
      #pragma unroll
      for (int hid=0;hid<32;++hid) acc=fmaf(h[hid], fc2_w[p*32+hid], acc);
      yv[p]=acc;
    }
    float smul = 3.0f + glv*wlv;
    float mu=0.f;
    #pragma unroll
    for (int p=0;p<16;++p) {
      yv[p]=fmaf(sl[rr*SROW_ + n*8 + p], smul, yv[p]);
      mu+=yv[p];
    }
    mu *= (1.0f/16.0f);
    float var=0.f;
    #pragma unroll
    for (int p=0;p<16;++p){ float d=yv[p]-mu; var=fmaf(d,d,var); }
    var *= (1.0f/16.0f);
    float rs = rsqrtf(var + EPS_);
    unsigned int wds[8];
    #pragma unroll
    for (int j=0;j<8;++j) {
      unsigned int lo = bf16bits(fmaf((yv[2*j]-mu)*rs,   ln_w[2*j],   ln_b[2*j]));
      unsigned int hi = bf16bits(fmaf((yv[2*j+1]-mu)*rs, ln_w[2*j+1], ln_b[2*j+1]));
      wds[j] = lo | (hi<<16);
    }
    size_t ybase = (size_t)(row0+rr)*1024 + n*16;
    uint4* dst = (uint4*)&ybf[ybase];
    dst[0] = make_uint4(wds[0],wds[1],wds[2],wds[3]);
    dst[1] = make_uint4(wds[4],wds[5],wds[6],wds[7]);
  }
}

// ---------- K5a_v2: pipeline from materialized cr (no fc1, no conv) ----------
__global__ __launch_bounds__(256) void k5a_v2(
    const float* __restrict__ s_raw, const float* __restrict__ wl_g,
    const __hip_bfloat16* __restrict__ crp,
    const float* __restrict__ scale1, const float* __restrict__ shift1,
    const float* __restrict__ conv_w, const float* __restrict__ conv_b,
    const float* __restrict__ scale2, const float* __restrict__ shift2,
    const float* __restrict__ fc2_w, const float* __restrict__ fc2_b,
    const float* __restrict__ gl_scale,
    const float* __restrict__ ln_w, const float* __restrict__ ln_b,
    __hip_bfloat16* __restrict__ ybf) {
  __shared__ float sl[RB_*SROW_];
  __shared__ float sc1[64], sh0l[64], shml[64], sh31l[64], sc2[64], sh2[64];
  int t = threadIdx.x;
  int row0 = blockIdx.x*RB_;
  if (t < 64) {
    float w0=conv_w[t*3], wm=conv_w[t*3+1], wp=conv_w[t*3+2];
    float s1v=shift1[t], cbv=conv_b[t];
    sc1[t]  = scale1[t];
    sh0l[t] = fmaf(s1v, wm+wp, cbv);
    shml[t] = fmaf(s1v, w0+wm+wp, cbv);
    sh31l[t]= fmaf(s1v, w0+wm, cbv);
    sc2[t]=scale2[t]; sh2[t]=shift2[t];
  }
  __syncthreads();
  for (int idx=t; idx<RB_*520; idx+=256) {
    int rr = idx/520, cc = idx - rr*520;
    sl[rr*SROW_+cc] = s_raw[(size_t)(row0+rr)*SROW_+cc];
  }
  __syncthreads();
  float glv = gl_scale[0];
  for (int idx=t; idx<RB_*64; idx+=256) {
    int rr = idx>>6, n = idx&63;
    float wlv = wl_g[(size_t)row0*64 + idx];
    const uint4* crb = (const uint4*)&crp[((size_t)(row0+rr)*64 + n)*32];
    uint4 u0=crb[0], u1=crb[1], u2=crb[2], u3=crb[3];
    unsigned uw[16] = {u0.x,u0.y,u0.z,u0.w, u1.x,u1.y,u1.z,u1.w,
                       u2.x,u2.y,u2.z,u2.w, u3.x,u3.y,u3.z,u3.w};
    float sc1n = sc1[n], sc2n = sc2[n], sh2n = sh2[n];
    float shm = shml[n];
    float yv[16];
    #pragma unroll
    for (int p=0;p<16;++p) yv[p] = fc2_b[p];
    #pragma unroll
    for (int j=0;j<16;++j) {
      unsigned u = uw[j];
      int k0 = 2*j, k1 = 2*j+1;
      float c0 = __uint_as_float(u<<16);
      float c1 = __uint_as_float(u & 0xffff0000u);
      float sh_0 = (j==0)  ? sh0l[n]  : shm;
      float sh_1 = (j==15) ? sh31l[n] : shm;
      float h2a = fmaf(gelu_f(fmaf(c0, sc1n, sh_0)), sc2n, sh2n);
      float h2b = fmaf(gelu_f(fmaf(c1, sc1n, sh_1)), sc2n, sh2n);
      #pragma unroll
      for (int p=0;p<16;++p)
        yv[p] = fmaf(h2a, fc2_w[p*32+k0], fmaf(h2b, fc2_w[p*32+k1], yv[p]));
    }
    float smul = 3.0f + glv*wlv;
    float mu=0.f;
    #pragma unroll
    for (int p=0;p<16;++p) {
      yv[p] = fmaf(sl[rr*SROW_ + n*8 + p], smul, yv[p]);
      mu += yv[p];
    }
    mu *= (1.0f/16.0f);
    float var=0.f;
    #pragma unroll
    for (int p=0;p<16;++p){ float d=yv[p]-mu; var=fmaf(d,d,var); }
    var *= (1.0f/16.0f);
    float rs = rsqrtf(var + EPS_);
    unsigned int wds[8];
    #pragma unroll
    for (int j=0;j<8;++j) {
      unsigned int lo = bf16bits(fmaf((yv[2*j]-mu)*rs,   ln_w[2*j],   ln_b[2*j]));
      unsigned int hi = bf16bits(fmaf((yv[2*j+1]-mu)*rs, ln_w[2*j+1], ln_b[2*j+1]));
      wds[j] = lo | (hi<<16);
    }
    size_t ybase = (size_t)(row0+rr)*1024 + n*16;
    uint4* dst = (uint4*)&ybf[ybase];
    dst[0] = make_uint4(wds[0],wds[1],wds[2],wds[3]);
    dst[1] = make_uint4(wds[4],wds[5],wds[6],wds[7]);
  }
}

// ---------- K5b: bf16 MFMA GEMM, double-buffered, merged 24-step K-loop ----------
__global__ __launch_bounds__(256) void k5b_gemm(
    const __hip_bfloat16* __restrict__ ybf, const __hip_bfloat16* __restrict__ tbf,
    const __hip_bfloat16* __restrict__ Wsf, const __hip_bfloat16* __restrict__ Wtf,
    const float* __restrict__ rowpar, const float* __restrict__ rev_b,
    const float* __restrict__ biasc, const float* __restrict__ colsumT,
    float* __restrict__ out) {
  __shared__ __align__(16) __hip_bfloat16 As[2*64*72];
  __shared__ __align__(16) __hip_bfloat16 Bs[2*96*72];
  __shared__ float rp[256];
  __shared__ float rbl[64];
  __shared__ int   obase[64];
  __shared__ float bcl[96], csl[96];
  int tid = threadIdx.x;
  int row0 = blockIdx.x*64;
  rp[tid] = rowpar[(size_t)row0*4 + tid];
  if (tid < 64) {
    int row = row0 + tid; int b = row/C_; int c = row - b*C_;
    rbl[tid] = rev_b[c]; obase[tid] = b*PRED_*C_ + c;
  }
  if (tid >= 128 && tid < 224) { bcl[tid-128]=biasc[tid-128]; csl[tid-128]=colsumT[tid-128]; }
  int lane = tid & 63, w = tid >> 6;
  int fr = lane & 15, fg = lane >> 4;
  int ra0 = tid>>3,       ca0 = tid&7;
  int ra1 = (tid+256)>>3, ca1 = (tid+256)&7;
  int rb0 = ra0, cb0_ = ca0;
  int rb1 = ra1, cb1_ = ca1;
  int rb2 = (tid+512)>>3, cb2_ = (tid+512)&7;
  f32x4 acc[6];
  #pragma unroll
  for (int n=0;n<6;++n) acc[n] = (f32x4){0.f,0.f,0.f,0.f};

  uint4 ar[2], br[3];
  auto LOAD = [&](int ks){
    if (ks < 8) {
      int kofs = ks*64;
      ar[0] = *(const uint4*)&tbf[(size_t)(row0+ra0)*512 + kofs + ca0*8];
      ar[1] = *(const uint4*)&tbf[(size_t)(row0+ra1)*512 + kofs + ca1*8];
      br[0] = *(const uint4*)&Wtf[(size_t)rb0*512 + kofs + cb0_*8];
      br[1] = *(const uint4*)&Wtf[(size_t)rb1*512 + kofs + cb1_*8];
      br[2] = *(const uint4*)&Wtf[(size_t)rb2*512 + kofs + cb2_*8];
    } else {
      int kofs = (ks-8)*64;
      ar[0] = *(const uint4*)&ybf[(size_t)(row0+ra0)*1024 + kofs + ca0*8];
      ar[1] = *(const uint4*)&ybf[(size_t)(row0+ra1)*1024 + kofs + ca1*8];
      br[0] = *(const uint4*)&Wsf[(size_t)rb0*1024 + kofs + cb0_*8];
      br[1] = *(const uint4*)&Wsf[(size_t)rb1*1024 + kofs + cb1_*8];
      br[2] = *(const uint4*)&Wsf[(size_t)rb2*1024 + kofs + cb2_*8];
    }
  };

  LOAD(0);
  int cur = 0;
  for (int ks=0; ks<24; ++ks) {
    __hip_bfloat16* Ab = &As[cur*64*72];
    __hip_bfloat16* Bb = &Bs[cur*96*72];
    *(uint4*)&Ab[ra0*72 + ca0*8] = ar[0];
    *(uint4*)&Ab[ra1*72 + ca1*8] = ar[1];
    *(uint4*)&Bb[rb0*72 + cb0_*8] = br[0];
    *(uint4*)&Bb[rb1*72 + cb1_*8] = br[1];
    *(uint4*)&Bb[rb2*72 + cb2_*8] = br[2];
    __syncthreads();
    if (ks < 23) LOAD(ks+1);
    #pragma unroll
    for (int ksub=0; ksub<2; ++ksub) {
      bf16x8 av = *(bf16x8*)&Ab[(w*16+fr)*72 + ksub*32 + fg*8];
      #pragma unroll
      for (int n=0;n<6;++n) {
        bf16x8 bv = *(bf16x8*)&Bb[(n*16+fr)*72 + ksub*32 + fg*8];
        acc[n] = __builtin_amdgcn_mfma_f32_16x16x32_bf16(av, bv, acc[n], 0,0,0);
      }
    }
    cur ^= 1;
  }
  #pragma unroll
  for (int n=0;n<6;++n) {
    int col = n*16 + fr;
    float cs = csl[col], bc = bcl[col];
    #pragma unroll
    for (int reg=0;reg<4;++reg) {
      int rloc = w*16 + fg*4 + reg;
      float g = rp[rloc*4+1], meanv = rp[rloc*4+2], inva = rp[rloc*4+3];
      float val = acc[n][reg] + g*cs + bc;
      val = (val - rbl[rloc])*inva + meanv;
      out[(size_t)obase[rloc] + (size_t)col*C_] = val;
    }
  }
}

extern "C" void kernel_launch(void* const* d_in, const int* in_sizes, int n_in,
                              void* d_out, int out_size, void* d_ws, size_t ws_size,
                              hipStream_t stream) {
  const float* x      = (const float*)d_in[0];
  const float* rev_w  = (const float*)d_in[1];
  const float* rev_b  = (const float*)d_in[2];
  const float* fc1_w  = (const float*)d_in[3];
  const float* fc1_b  = (const float*)d_in[4];
  const float* bn1_w  = (const float*)d_in[5];
  const float* bn1_b  = (const float*)d_in[6];
  const float* conv_w = (const float*)d_in[7];
  const float* conv_b = (const float*)d_in[8];
  const float* bn2_w  = (const float*)d_in[9];
  const float* bn2_b  = (const float*)d_in[10];
  const float* fc2_w  = (const float*)d_in[11];
  const float* fc2_b  = (const float*)d_in[12];
  const float* m1_w   = (const float*)d_in[13];
  const float* m1_b   = (const float*)d_in[14];
  const float* m2_w   = (const float*)d_in[15];
  const float* m2_b   = (const float*)d_in[16];
  const float* gl     = (const float*)d_in[17];
  const float* ln_w   = (const float*)d_in[18];
  const float* ln_b   = (const float*)d_in[19];
  const float* seas_w = (const float*)d_in[20];
  const float* seas_b = (const float*)d_in[21];
  const float* tr_w   = (const float*)d_in[22];
  const float* tr_b   = (const float*)d_in[23];
  const float* fus_w  = (const float*)d_in[24];
  const float* fus_b  = (const float*)d_in[25];
  float* out = (float*)d_out;
  float* ws = (float*)d_ws;

  __hip_bfloat16* Wsf  = (__hip_bfloat16*)(ws);
  __hip_bfloat16* Wtf  = (__hip_bfloat16*)(ws + 49152);
  float* biasc   = ws + 73728;
  float* colsumT = ws + 73856;
  float* scale1  = ws + 73984;
  float* shift1  = ws + 74048;
  float* scale2  = ws + 74112;
  float* shift2  = ws + 74176;
  float* partials= ws + 74240;
  float* rowpar  = ws + 238592;
  float* s_raw   = ws + 320768;
  __hip_bfloat16* t_bf = (__hip_bfloat16*)(ws + 11168000);
  __hip_bfloat16* ybf  = (__hip_bfloat16*)(ws + 16427264);
  float* pooled  = ws + 26945792;
  float* wl_g    = ws + 28260608;
  __hip_bfloat16* crp  = (__hip_bfloat16*)(ws + 29575424);  // BC*2048 bf16
  const size_t NEED = (29575424ull + 21037056ull) * 4ull;   // ~202.5 MB
  bool big = (ws_size >= NEED);

  hipLaunchKernelGGL(k0_fold,  dim3(576),  dim3(256), 0, stream, seas_w, tr_w, fus_w, Wsf, Wtf);
  hipLaunchKernelGGL(k0b_bias, dim3(1),    dim3(128), 0, stream, seas_b, tr_b, fus_w, fus_b, tr_w, biasc, colsumT);
  hipLaunchKernelGGL(k1_revin_ema, dim3(BC_/32), dim3(256), 0, stream, x, rev_w, rev_b, s_raw, t_bf, rowpar, pooled);
  hipLaunchKernelGGL(k4_gate, dim3(BC_/64), dim3(256), 0, stream, pooled, m1_w, m1_b, m2_w, m2_b, wl_g);
  if (big) {
    hipLaunchKernelGGL(k2v2_bn1_cr, dim3(NBLK2_), dim3(256), 0, stream, s_raw, fc1_w, fc1_b, conv_w, partials, crp);
    hipLaunchKernelGGL(k_bnreduce, dim3(64), dim3(256), 0, stream, partials, NBLK2_, bn1_w, bn1_b, scale1, shift1);
    hipLaunchKernelGGL(k3v2_bn2stats, dim3(NBLK2_), dim3(256), 0, stream, crp, scale1, shift1, conv_w, conv_b, partials);
    hipLaunchKernelGGL(k_bnreduce, dim3(64), dim3(256), 0, stream, partials, NBLK2_, bn2_w, bn2_b, scale2, shift2);
    hipLaunchKernelGGL(k5a_v2, dim3(BC_/RB_), dim3(256), 0, stream,
      s_raw, wl_g, crp, scale1, shift1, conv_w, conv_b,
      scale2, shift2, fc2_w, fc2_b, gl, ln_w, ln_b, ybf);
  } else {
    hipLaunchKernelGGL(k2_bn1stats, dim3(NBLK2_), dim3(256), 0, stream, s_raw, fc1_w, fc1_b, partials);
    hipLaunchKernelGGL(k_bnreduce, dim3(64), dim3(256), 0, stream, partials, NBLK2_, bn1_w, bn1_b, scale1, shift1);
    hipLaunchKernelGGL(k3_bn2stats, dim3(NBLK2_), dim3(256), 0, stream, s_raw, fc1_w, fc1_b, scale1, shift1, conv_w, conv_b, partials);
    hipLaunchKernelGGL(k_bnreduce, dim3(64), dim3(256), 0, stream, partials, NBLK2_, bn2_w, bn2_b, scale2, shift2);
    hipLaunchKernelGGL(k5a_pipeline, dim3(BC_/RB_), dim3(256), 0, stream,
      s_raw, wl_g, fc1_w, fc1_b, scale1, shift1, conv_w, conv_b,
      scale2, shift2, fc2_w, fc2_b, gl, ln_w, ln_b, ybf);
  }
  hipLaunchKernelGGL(k5b_gemm, dim3(BC_/64), dim3(256), 0, stream,
    ybf, t_bf, Wsf, Wtf, rowpar, rev_b, biasc, colsumT, out);
}

// Round 11
// 332.393 us; speedup vs baseline: 1.4486x; 1.2736x over previous
//
#include <hip/hip_runtime.h>
#include <hip/hip_bf16.h>
#include <math.h>

#define B_    64
#define L_    512
#define C_    321
#define PRED_ 96
#define N_    64
#define HID_  32
#define BC_   (B_*C_)   // 20544
#define SROW_ 528
#define EPS_  1e-5f
#define ALPHA_ 0.2f
#define GR_   16
#define RB_   8
#define NBLK2_ (BC_/GR_) // 1284
#define D64_  6.2771017353866808e-7f   // 0.8^64
#define STW_  548   // f32 stage stride: 548&31==4 -> <=4-way fill conflicts
#define UTW_  260   // uint stage stride for t (260&31==4)

typedef __attribute__((ext_vector_type(8))) short bf16x8;
typedef __attribute__((ext_vector_type(4))) float f32x4;

// Fast gelu: A&S 7.1.26 erf approx, |eps|<=1.5e-7, branch-free.
__device__ __forceinline__ float gelu_f(float x){
  float ax = fabsf(x);
  float z  = ax * 0.70710678118654752440f;
  float t  = __builtin_amdgcn_rcpf(fmaf(0.3275911f, z, 1.0f));
  float poly = fmaf(fmaf(fmaf(fmaf(1.061405429f, t, -1.453152027f),
                   t, 1.421413741f), t, -0.284496736f), t, 0.254829592f) * t;
  float e  = __expf(-z*z);
  float erfp = fmaf(-poly, e, 1.0f);
  return fmaf(0.5f*ax, erfp, 0.5f*x);
}
__device__ __forceinline__ unsigned short bf16bits(float x){
  __hip_bfloat16 h = __float2bfloat16(x);
  return *(unsigned short*)&h;
}

// ---------- K0: fold seas/tr matmuls through fus; bf16 col-major [j][k] ----------
__global__ __launch_bounds__(256) void k0_fold(
    const float* __restrict__ seas_w, const float* __restrict__ tr_w,
    const float* __restrict__ fus_w,
    __hip_bfloat16* __restrict__ Wsf, __hip_bfloat16* __restrict__ Wtf) {
  int idx = blockIdx.x*256 + threadIdx.x;
  if (idx >= 96*1536) return;
  int j = idx / 1536, k = idx - j*1536;
  float acc = 0.f;
  if (k < 1024) {
    for (int i=0;i<96;++i) acc = fmaf(fus_w[j*192+i], seas_w[i*1024+k], acc);
    Wsf[(size_t)j*1024 + k] = __float2bfloat16(acc);
  } else {
    int l = k - 1024;
    for (int i=0;i<96;++i) acc = fmaf(fus_w[j*192+96+i], tr_w[i*512+l], acc);
    Wtf[(size_t)j*512 + l] = __float2bfloat16(acc);
  }
}

// ---------- K0b ----------
__global__ void k0b_bias(
    const float* __restrict__ seas_b, const float* __restrict__ tr_b,
    const float* __restrict__ fus_w, const float* __restrict__ fus_b,
    const float* __restrict__ tr_w,
    float* __restrict__ biasc, float* __restrict__ colsumT) {
  __shared__ float rowsum[96];
  int t = threadIdx.x;
  if (t < 96) {
    float s = 0.f;
    for (int l=0;l<512;++l) s += tr_w[t*512+l];
    rowsum[t] = s;
  }
  __syncthreads();
  if (t < 96) {
    float acc = fus_b[t], cs = 0.f;
    for (int i=0;i<96;++i) {
      acc = fmaf(fus_w[t*192+i],    seas_b[i], acc);
      acc = fmaf(fus_w[t*192+96+i], tr_b[i],   acc);
      cs  = fmaf(fus_w[t*192+96+i], rowsum[i], cs);
    }
    biasc[t] = acc; colsumT[t] = cs;
  }
}

// ---------- K1: RevIN + EMA, single x read, LDS-staged COALESCED stores ----------
__global__ __launch_bounds__(256) void k1_revin_ema(
    const float* __restrict__ x, const float* __restrict__ rev_w, const float* __restrict__ rev_b,
    float* __restrict__ s_raw, __hip_bfloat16* __restrict__ t_bf, float* __restrict__ rowpar,
    float* __restrict__ pooled) {
  __shared__ float lf[8][32];
  __shared__ float psum[8][32], psq[8][32];
  __shared__ float fs[8][32];
  __shared__ float st[32*STW_];
  int tid = threadIdx.x;
  int q = tid >> 5, r = tid & 31;
  int row0 = blockIdx.x*32;
  int row = row0 + r;
  int b = row / C_, c = row - b*C_;
  const float* xp = x + (size_t)b*L_*C_ + c;
  int l0 = q*64;
  float sreg[64];
  float loc = 0.f, sum = 0.f, sq = 0.f;
  #pragma unroll
  for (int i=0;i<64;++i) {
    float v = xp[(size_t)(l0+i)*C_];
    sum += v; sq = fmaf(v,v,sq);
    loc = (q==0 && i==0) ? v : fmaf(ALPHA_, v, 0.8f*loc);
    sreg[i] = loc;
  }
  lf[q][r] = loc; psum[q][r] = sum; psq[q][r] = sq;
  __syncthreads();
  float cin = 0.f;
  for (int j=0;j<q;++j) cin = fmaf(D64_, cin, lf[j][r]);
  float S=0.f, Q=0.f;
  #pragma unroll
  for (int qq=0;qq<8;++qq){ S += psum[qq][r]; Q += psq[qq][r]; }
  float mean = S*(1.0f/512.0f);
  float var  = (Q - S*S*(1.0f/512.0f))*(1.0f/511.0f);
  var = fmaxf(var, 0.f);
  float stdv = sqrtf(var) + EPS_;
  float rwc = rev_w[c];
  float a = rwc / stdv;
  if (q==0) {
    float rbc = rev_b[c];
    float g = rbc - mean*a;
    float inva = stdv / rwc;
    ((float4*)rowpar)[row] = make_float4(a, g, mean, inva);
  }
  float prev = 0.f, f = 1.f, slast = 0.f;
  float sums8[8];
  #pragma unroll
  for (int j=0;j<8;++j) sums8[j] = 0.f;
  #pragma unroll
  for (int i=0;i<64;++i) {
    float lc = sreg[i];
    f *= 0.8f;
    float s = (q==0 && i==0) ? 0.f : fmaf(4.f, lc - prev, -f*cin);
    prev = lc;
    float sv = s * a;
    st[r*STW_ + q*64 + i] = sv;
    sums8[i>>3] += sv;
    slast = sv;
  }
  fs[q][r] = sums8[0];
  if (q==7) {
    #pragma unroll
    for (int k=0;k<8;++k) st[r*STW_ + 512 + k] = slast;
  }
  __syncthreads();
  for (int idx=tid; idx<32*130; idx+=256) {
    int rr = idx/130, g = idx - rr*130;
    float4 v = *(float4*)&st[rr*STW_ + g*4];
    *(float4*)&s_raw[(size_t)(row0+rr)*SROW_ + g*4] = v;
  }
  {
    float nf = (q < 7) ? fs[q+1][r] : 8.0f*slast;
    #pragma unroll
    for (int j=0;j<7;++j)
      pooled[(size_t)row*64 + q*8 + j] = (sums8[j] + sums8[j+1])*(1.0f/16.0f);
    pooled[(size_t)row*64 + q*8 + 7] = (sums8[7] + nf)*(1.0f/16.0f);
  }
  __syncthreads();
  unsigned* tb = (unsigned*)st;
  {
    float f2 = 1.f; unsigned lo = 0;
    #pragma unroll
    for (int i=0;i<64;++i) {
      f2 *= 0.8f;
      float tt = fmaf(f2, cin, sreg[i]) * a;
      unsigned hb = bf16bits(tt);
      if ((i&1)==0) lo = hb;
      else tb[r*UTW_ + q*32 + (i>>1)] = lo | (hb<<16);
    }
  }
  __syncthreads();
  for (int idx=tid; idx<32*64; idx+=256) {
    int rr = idx>>6, g = idx&63;
    uint4 v = *(uint4*)&tb[rr*UTW_ + g*4];
    *(uint4*)&t_bf[(size_t)(row0+rr)*512 + g*8] = v;
  }
}

// ---------- K4: gate MLP ----------
__global__ __launch_bounds__(256) void k4_gate(
    const float* __restrict__ pooled,
    const float* __restrict__ m1_w, const float* __restrict__ m1_b,
    const float* __restrict__ m2_w, const float* __restrict__ m2_b,
    float* __restrict__ wl_g) {
  __shared__ float pl[64][65];
  __shared__ float h1[64][129];
  int t = threadIdx.x;
  int row0 = blockIdx.x*64;
  for (int idx=t; idx<4096; idx+=256)
    pl[idx>>6][idx&63] = pooled[(size_t)row0*64 + idx];
  __syncthreads();
  int w = t>>6, l = t&63;
  for (int ii=0; ii<32; ++ii) {
    int i = w*32 + ii;
    float acc = m1_b[i];
    #pragma unroll
    for (int k=0;k<64;++k) acc = fmaf(pl[l][k], m1_w[i*64+k], acc);
    h1[l][i] = gelu_f(acc);
  }
  __syncthreads();
  for (int jj=0; jj<16; ++jj) {
    int n = w*16 + jj;
    float acc = m2_b[n];
    #pragma unroll
    for (int k=0;k<128;++k) acc = fmaf(h1[l][k], m2_w[n*128+k], acc);
    wl_g[(size_t)(row0+l)*64 + n] = 1.0f/(1.0f + __expf(-acc));
  }
}

// ---------- K2 (fallback): BN1 statistics ----------
__global__ __launch_bounds__(256) void k2_bn1stats(
    const float* __restrict__ s_raw,
    const float* __restrict__ fc1_w, const float* __restrict__ fc1_b,
    float* __restrict__ partials) {
  __shared__ float sl[GR_*SROW_];
  __shared__ float red[2][GR_*64];
  int t = threadIdx.x;
  int row0 = blockIdx.x*GR_;
  for (int idx=t; idx<GR_*520; idx+=256) {
    int rr = idx/520, cc = idx - rr*520;
    sl[rr*SROW_+cc] = s_raw[(size_t)(row0+rr)*SROW_+cc];
  }
  __syncthreads();
  int lr = t >> 4, ng = t & 15;
  for (int q=0;q<4;++q) {
    int n = ng + 16*q;
    float sp[16];
    #pragma unroll
    for (int p=0;p<16;++p) sp[p] = sl[lr*SROW_ + n*8 + p];
    float s1=0.f, s2=0.f;
    #pragma unroll
    for (int hid=0; hid<32; ++hid) {
      float acc = fc1_b[hid];
      #pragma unroll
      for (int p=0;p<16;++p) acc = fmaf(sp[p], fc1_w[hid*16+p], acc);
      float gv = gelu_f(acc);
      s1 += gv; s2 = fmaf(gv,gv,s2);
    }
    red[0][lr*64+n] = s1;
    red[1][lr*64+n] = s2;
  }
  __syncthreads();
  if (t < 64) {
    float S1=0.f, S2=0.f;
    for (int lr2=0; lr2<GR_; ++lr2) { S1 += red[0][lr2*64+t]; S2 += red[1][lr2*64+t]; }
    partials[((size_t)blockIdx.x*64+t)*2+0] = S1;
    partials[((size_t)blockIdx.x*64+t)*2+1] = S2;
  }
}

// ---------- K2v2: 512-thread BN1 stats + materialize cr bf16 ----------
__global__ __launch_bounds__(512) void k2v2_bn1_cr(
    const float* __restrict__ s_raw,
    const float* __restrict__ fc1_w, const float* __restrict__ fc1_b,
    const float* __restrict__ conv_w,
    float* __restrict__ partials, __hip_bfloat16* __restrict__ crp) {
  __shared__ float sl[GR_*SROW_];
  __shared__ float cw[192];
  __shared__ float red[2][GR_*64];
  int t = threadIdx.x;
  int row0 = blockIdx.x*GR_;
  if (t < 192) cw[t] = conv_w[t];
  for (int idx=t; idx<GR_*520; idx+=512) {
    int rr = idx/520, cc = idx - rr*520;
    sl[rr*SROW_+cc] = s_raw[(size_t)(row0+rr)*SROW_+cc];
  }
  __syncthreads();
  #pragma unroll
  for (int q=0;q<2;++q) {
    int item = t + q*512;
    int lr = item>>6, n = item&63;
    float sp[16];
    #pragma unroll
    for (int p=0;p<16;++p) sp[p] = sl[lr*SROW_ + n*8 + p];
    float w0=cw[n*3], wm=cw[n*3+1], wp=cw[n*3+2];
    float s1=0.f, s2=0.f;
    auto gf = [&](int k)->float {
      float acc = fc1_b[k];
      #pragma unroll
      for (int p=0;p<16;++p) acc = fmaf(sp[p], fc1_w[k*16+p], acc);
      float g = gelu_f(acc);
      s1 += g; s2 = fmaf(g,g,s2);
      return g;
    };
    float gm = 0.f, gc = gf(0), gp = gf(1);
    unsigned wds[16]; unsigned crlo = 0;
    #pragma unroll
    for (int k=0;k<32;++k) {
      float cr = fmaf(gm, w0, fmaf(gc, wm, (k<31) ? gp*wp : 0.f));
      unsigned hb = bf16bits(cr);
      if ((k&1)==0) crlo = hb; else wds[k>>1] = crlo | (hb<<16);
      gm = gc; gc = gp;
      gp = (k+2<32) ? gf(k+2) : 0.f;
    }
    uint4* dst = (uint4*)&crp[((size_t)(row0+lr)*64 + n)*32];
    dst[0] = make_uint4(wds[0],wds[1],wds[2],wds[3]);
    dst[1] = make_uint4(wds[4],wds[5],wds[6],wds[7]);
    dst[2] = make_uint4(wds[8],wds[9],wds[10],wds[11]);
    dst[3] = make_uint4(wds[12],wds[13],wds[14],wds[15]);
    red[0][item] = s1;
    red[1][item] = s2;
  }
  __syncthreads();
  if (t < 64) {
    float S1=0.f, S2=0.f;
    for (int lr2=0; lr2<GR_; ++lr2) { S1 += red[0][lr2*64+t]; S2 += red[1][lr2*64+t]; }
    partials[((size_t)blockIdx.x*64+t)*2+0] = S1;
    partials[((size_t)blockIdx.x*64+t)*2+1] = S2;
  }
}

// ---------- bn reduce ----------
__global__ __launch_bounds__(256) void k_bnreduce(
    const float* __restrict__ partials, int nblk,
    const float* __restrict__ bnw, const float* __restrict__ bnb,
    float* __restrict__ scale, float* __restrict__ shift) {
  __shared__ float red[2][256];
  int n = blockIdx.x, t = threadIdx.x;
  float s1=0.f, s2=0.f;
  for (int i=t; i<nblk; i+=256) {
    s1 += partials[((size_t)i*64+n)*2+0];
    s2 += partials[((size_t)i*64+n)*2+1];
  }
  red[0][t]=s1; red[1][t]=s2;
  __syncthreads();
  for (int off=128; off>0; off>>=1) {
    if (t<off) { red[0][t]+=red[0][t+off]; red[1][t]+=red[1][t+off]; }
    __syncthreads();
  }
  if (t==0) {
    const float count = (float)BC_ * 32.0f;
    float mu = red[0][0]/count;
    float var = red[1][0]/count - mu*mu;
    float sc = rsqrtf(var + EPS_) * bnw[n];
    scale[n] = sc;
    shift[n] = bnb[n] - mu*sc;
  }
}

// ---------- K3 (fallback): BN2 statistics ----------
__global__ __launch_bounds__(256) void k3_bn2stats(
    const float* __restrict__ s_raw,
    const float* __restrict__ fc1_w, const float* __restrict__ fc1_b,
    const float* __restrict__ scale1, const float* __restrict__ shift1,
    const float* __restrict__ conv_w, const float* __restrict__ conv_b,
    float* __restrict__ partials) {
  __shared__ float sl[GR_*SROW_];
  __shared__ float sc1[64], sh1[64], cw[192], cb[64];
  __shared__ float red[2][GR_*64];
  int t = threadIdx.x;
  int row0 = blockIdx.x*GR_;
  if (t < 64) { sc1[t]=scale1[t]; sh1[t]=shift1[t]; cb[t]=conv_b[t]; }
  if (t >= 64 && t < 256) cw[t-64] = conv_w[t-64];
  __syncthreads();
  for (int idx=t; idx<GR_*520; idx+=256) {
    int rr = idx/520, cc = idx - rr*520;
    sl[rr*SROW_+cc] = s_raw[(size_t)(row0+rr)*SROW_+cc];
  }
  __syncthreads();
  int lr = t >> 4, ng = t & 15;
  for (int q=0;q<4;++q) {
    int n = ng + 16*q;
    float sp[16];
    #pragma unroll
    for (int p=0;p<16;++p) sp[p] = sl[lr*SROW_ + n*8 + p];
    float scn = sc1[n], shn = sh1[n];
    float h[32];
    #pragma unroll
    for (int hid=0; hid<32; ++hid) {
      float acc = fc1_b[hid];
      #pragma unroll
      for (int p=0;p<16;++p) acc = fmaf(sp[p], fc1_w[hid*16+p], acc);
      h[hid] = fmaf(gelu_f(acc), scn, shn);
    }
    float w0=cw[n*3], wm=cw[n*3+1], wpp=cw[n*3+2], cbn=cb[n];
    float s1=0.f, s2=0.f, prev=0.f;
    #pragma unroll
    for (int k2=0;k2<32;++k2) {
      float cur = h[k2];
      float cv = cbn;
      cv = fmaf(prev, w0, cv);
      cv = fmaf(cur, wm, cv);
      if (k2<31) cv = fmaf(h[k2+1], wpp, cv);
      float gv = gelu_f(cv);
      s1 += gv; s2 = fmaf(gv,gv,s2);
      prev = cur;
    }
    red[0][lr*64+n]=s1; red[1][lr*64+n]=s2;
  }
  __syncthreads();
  if (t < 64) {
    float S1=0.f, S2=0.f;
    for (int lr2=0; lr2<GR_; ++lr2) { S1 += red[0][lr2*64+t]; S2 += red[1][lr2*64+t]; }
    partials[((size_t)blockIdx.x*64+t)*2+0] = S1;
    partials[((size_t)blockIdx.x*64+t)*2+1] = S2;
  }
}

// ---------- K3v2: 512-thread BN2 stats from materialized cr ----------
__global__ __launch_bounds__(512) void k3v2_bn2stats(
    const __hip_bfloat16* __restrict__ crp,
    const float* __restrict__ scale1, const float* __restrict__ shift1,
    const float* __restrict__ conv_w, const float* __restrict__ conv_b,
    float* __restrict__ partials) {
  __shared__ float sc1[64], sh0l[64], shml[64], sh31l[64];
  __shared__ float red[2][GR_*64];
  int t = threadIdx.x;
  int row0 = blockIdx.x*GR_;
  if (t < 64) {
    float w0=conv_w[t*3], wm=conv_w[t*3+1], wp=conv_w[t*3+2];
    float s1v=shift1[t], cbv=conv_b[t];
    sc1[t]  = scale1[t];
    sh0l[t] = fmaf(s1v, wm+wp, cbv);
    shml[t] = fmaf(s1v, w0+wm+wp, cbv);
    sh31l[t]= fmaf(s1v, w0+wm, cbv);
  }
  __syncthreads();
  #pragma unroll
  for (int q=0;q<2;++q) {
    int item = t + q*512;
    int lr = item>>6, n = item&63;
    const uint4* crb = (const uint4*)&crp[((size_t)(row0+lr)*64 + n)*32];
    uint4 u0=crb[0], u1=crb[1], u2=crb[2], u3=crb[3];
    unsigned uw[16] = {u0.x,u0.y,u0.z,u0.w, u1.x,u1.y,u1.z,u1.w,
                       u2.x,u2.y,u2.z,u2.w, u3.x,u3.y,u3.z,u3.w};
    float sc1n = sc1[n];
    float shm = shml[n];
    float s1=0.f, s2=0.f;
    #pragma unroll
    for (int j=0;j<16;++j) {
      unsigned u = uw[j];
      float c0 = __uint_as_float(u<<16);
      float c1 = __uint_as_float(u & 0xffff0000u);
      float sh_0 = (j==0)  ? sh0l[n]  : shm;
      float sh_1 = (j==15) ? sh31l[n] : shm;
      float g0 = gelu_f(fmaf(c0, sc1n, sh_0));
      float g1 = gelu_f(fmaf(c1, sc1n, sh_1));
      s1 += g0 + g1;
      s2 = fmaf(g0,g0, fmaf(g1,g1, s2));
    }
    red[0][item]=s1; red[1][item]=s2;
  }
  __syncthreads();
  if (t < 64) {
    float S1=0.f, S2=0.f;
    for (int lr2=0; lr2<GR_; ++lr2) { S1 += red[0][lr2*64+t]; S2 += red[1][lr2*64+t]; }
    partials[((size_t)blockIdx.x*64+t)*2+0] = S1;
    partials[((size_t)blockIdx.x*64+t)*2+1] = S2;
  }
}

// ---------- K5a (fallback): full per-row pipeline ----------
__global__ __launch_bounds__(256) void k5a_pipeline(
    const float* __restrict__ s_raw, const float* __restrict__ wl_g,
    const float* __restrict__ fc1_w, const float* __restrict__ fc1_b,
    const float* __restrict__ scale1, const float* __restrict__ shift1,
    const float* __restrict__ conv_w, const float* __restrict__ conv_b,
    const float* __restrict__ scale2, const float* __restrict__ shift2,
    const float* __restrict__ fc2_w, const float* __restrict__ fc2_b,
    const float* __restrict__ gl_scale,
    const float* __restrict__ ln_w, const float* __restrict__ ln_b,
    __hip_bfloat16* __restrict__ ybf) {
  __shared__ float sl[RB_*SROW_];
  __shared__ float cw[192], cb[64];
  __shared__ float sc1[64], sh1[64], sc2[64], sh2[64];
  int t = threadIdx.x;
  int row0 = blockIdx.x*RB_;
  if (t<64) { sc1[t]=scale1[t]; sh1[t]=shift1[t]; sc2[t]=scale2[t]; sh2[t]=shift2[t]; cb[t]=conv_b[t]; }
  if (t>=64 && t<256) cw[t-64]=conv_w[t-64];
  __syncthreads();
  for (int idx=t; idx<RB_*520; idx+=256) {
    int rr = idx/520, cc = idx - rr*520;
    sl[rr*SROW_+cc] = s_raw[(size_t)(row0+rr)*SROW_+cc];
  }
  __syncthreads();
  float glv = gl_scale[0];
  for (int idx=t; idx<RB_*64; idx+=256) {
    int rr = idx>>6, n = idx&63;
    float wlv = wl_g[(size_t)row0*64 + idx];
    float h[32];
    {
      float sp[16];
      #pragma unroll
      for (int p=0;p<16;++p) sp[p] = sl[rr*SROW_ + n*8 + p];
      float scn=sc1[n], shn=sh1[n];
      #pragma unroll
      for (int hid=0;hid<32;++hid) {
        float acc=fc1_b[hid];
        #pragma unroll
        for (int p=0;p<16;++p) acc=fmaf(sp[p], fc1_w[hid*16+p], acc);
        h[hid]=fmaf(gelu_f(acc), scn, shn);
      }
    }
    {
      float w0=cw[n*3], wm=cw[n*3+1], wpp=cw[n*3+2], cbn=cb[n];
      float sc2n=sc2[n], sh2n=sh2[n];
      float prev=0.f;
      #pragma unroll
      for (int k2=0;k2<32;++k2) {
        float cur = h[k2];
        float cv = cbn;
        cv = fmaf(prev, w0, cv);
        cv = fmaf(cur, wm, cv);
        if (k2<31) cv = fmaf(h[k2+1], wpp, cv);
        h[k2] = fmaf(gelu_f(cv), sc2n, sh2n);
        prev = cur;
      }
    }
    float yv[16];
    #pragma unroll
    for (int p=0;p<16;++p) {
      float acc=fc2_b[p];
      #pragma unroll
      for (int hid=0;hid<32;++hid) acc=fmaf(h[hid], fc2_w[p*32+hid], acc);
      yv[p]=acc;
    }
    float smul = 3.0f + glv*wlv;
    float mu=0.f;
    #pragma unroll
    for (int p=0;p<16;++p) {
      yv[p]=fmaf(sl[rr*SROW_ + n*8 + p], smul, yv[p]);
      mu+=yv[p];
    }
    mu *= (1.0f/16.0f);
    float var=0.f;
    #pragma unroll
    for (int p=0;p<16;++p){ float d=yv[p]-mu; var=fmaf(d,d,var); }
    var *= (1.0f/16.0f);
    float rs = rsqrtf(var + EPS_);
    unsigned int wds[8];
    #pragma unroll
    for (int j=0;j<8;++j) {
      unsigned int lo = bf16bits(fmaf((yv[2*j]-mu)*rs,   ln_w[2*j],   ln_b[2*j]));
      unsigned int hi = bf16bits(fmaf((yv[2*j+1]-mu)*rs, ln_w[2*j+1], ln_b[2*j+1]));
      wds[j] = lo | (hi<<16);
    }
    size_t ybase = (size_t)(row0+rr)*1024 + n*16;
    uint4* dst = (uint4*)&ybf[ybase];
    dst[0] = make_uint4(wds[0],wds[1],wds[2],wds[3]);
    dst[1] = make_uint4(wds[4],wds[5],wds[6],wds[7]);
  }
}

// ---------- K5a_v2: 512-thread pipeline from materialized cr ----------
__global__ __launch_bounds__(512) void k5a_v2(
    const float* __restrict__ s_raw, const float* __restrict__ wl_g,
    const __hip_bfloat16* __restrict__ crp,
    const float* __restrict__ scale1, const float* __restrict__ shift1,
    const float* __restrict__ conv_w, const float* __restrict__ conv_b,
    const float* __restrict__ scale2, const float* __restrict__ shift2,
    const float* __restrict__ fc2_w, const float* __restrict__ fc2_b,
    const float* __restrict__ gl_scale,
    const float* __restrict__ ln_w, const float* __restrict__ ln_b,
    __hip_bfloat16* __restrict__ ybf) {
  __shared__ float sl[RB_*SROW_];
  __shared__ float sc1[64], sh0l[64], shml[64], sh31l[64], sc2[64], sh2[64];
  int t = threadIdx.x;
  int row0 = blockIdx.x*RB_;
  if (t < 64) {
    float w0=conv_w[t*3], wm=conv_w[t*3+1], wp=conv_w[t*3+2];
    float s1v=shift1[t], cbv=conv_b[t];
    sc1[t]  = scale1[t];
    sh0l[t] = fmaf(s1v, wm+wp, cbv);
    shml[t] = fmaf(s1v, w0+wm+wp, cbv);
    sh31l[t]= fmaf(s1v, w0+wm, cbv);
    sc2[t]=scale2[t]; sh2[t]=shift2[t];
  }
  __syncthreads();
  for (int idx=t; idx<RB_*520; idx+=512) {
    int rr = idx/520, cc = idx - rr*520;
    sl[rr*SROW_+cc] = s_raw[(size_t)(row0+rr)*SROW_+cc];
  }
  __syncthreads();
  float glv = gl_scale[0];
  {
    int idx = t;
    int rr = idx>>6, n = idx&63;
    float wlv = wl_g[(size_t)row0*64 + idx];
    const uint4* crb = (const uint4*)&crp[((size_t)(row0+rr)*64 + n)*32];
    uint4 u0=crb[0], u1=crb[1], u2=crb[2], u3=crb[3];
    unsigned uw[16] = {u0.x,u0.y,u0.z,u0.w, u1.x,u1.y,u1.z,u1.w,
                       u2.x,u2.y,u2.z,u2.w, u3.x,u3.y,u3.z,u3.w};
    float sc1n = sc1[n], sc2n = sc2[n], sh2n = sh2[n];
    float shm = shml[n];
    float yv[16];
    #pragma unroll
    for (int p=0;p<16;++p) yv[p] = fc2_b[p];
    #pragma unroll
    for (int j=0;j<16;++j) {
      unsigned u = uw[j];
      int k0 = 2*j, k1 = 2*j+1;
      float c0 = __uint_as_float(u<<16);
      float c1 = __uint_as_float(u & 0xffff0000u);
      float sh_0 = (j==0)  ? sh0l[n]  : shm;
      float sh_1 = (j==15) ? sh31l[n] : shm;
      float h2a = fmaf(gelu_f(fmaf(c0, sc1n, sh_0)), sc2n, sh2n);
      float h2b = fmaf(gelu_f(fmaf(c1, sc1n, sh_1)), sc2n, sh2n);
      #pragma unroll
      for (int p=0;p<16;++p)
        yv[p] = fmaf(h2a, fc2_w[p*32+k0], fmaf(h2b, fc2_w[p*32+k1], yv[p]));
    }
    float smul = 3.0f + glv*wlv;
    float mu=0.f;
    #pragma unroll
    for (int p=0;p<16;++p) {
      yv[p] = fmaf(sl[rr*SROW_ + n*8 + p], smul, yv[p]);
      mu += yv[p];
    }
    mu *= (1.0f/16.0f);
    float var=0.f;
    #pragma unroll
    for (int p=0;p<16;++p){ float d=yv[p]-mu; var=fmaf(d,d,var); }
    var *= (1.0f/16.0f);
    float rs = rsqrtf(var + EPS_);
    unsigned int wds[8];
    #pragma unroll
    for (int j=0;j<8;++j) {
      unsigned int lo = bf16bits(fmaf((yv[2*j]-mu)*rs,   ln_w[2*j],   ln_b[2*j]));
      unsigned int hi = bf16bits(fmaf((yv[2*j+1]-mu)*rs, ln_w[2*j+1], ln_b[2*j+1]));
      wds[j] = lo | (hi<<16);
    }
    size_t ybase = (size_t)(row0+rr)*1024 + n*16;
    uint4* dst = (uint4*)&ybf[ybase];
    dst[0] = make_uint4(wds[0],wds[1],wds[2],wds[3]);
    dst[1] = make_uint4(wds[4],wds[5],wds[6],wds[7]);
  }
}

// ---------- K5b: bf16 MFMA GEMM, M=32 tiles, double-buffered ----------
__global__ __launch_bounds__(256) void k5b_gemm(
    const __hip_bfloat16* __restrict__ ybf, const __hip_bfloat16* __restrict__ tbf,
    const __hip_bfloat16* __restrict__ Wsf, const __hip_bfloat16* __restrict__ Wtf,
    const float* __restrict__ rowpar, const float* __restrict__ rev_b,
    const float* __restrict__ biasc, const float* __restrict__ colsumT,
    float* __restrict__ out) {
  __shared__ __align__(16) __hip_bfloat16 As[2*32*72];
  __shared__ __align__(16) __hip_bfloat16 Bs[2*96*72];
  __shared__ float rp[128];
  __shared__ float rbl[32];
  __shared__ int   obase[32];
  __shared__ float bcl[96], csl[96];
  int tid = threadIdx.x;
  int row0 = blockIdx.x*32;
  if (tid < 128) rp[tid] = rowpar[(size_t)row0*4 + tid];
  if (tid >= 128 && tid < 160) {
    int lr = tid-128;
    int row = row0 + lr; int b = row/C_; int c = row - b*C_;
    rbl[lr] = rev_b[c]; obase[lr] = b*PRED_*C_ + c;
  }
  if (tid >= 160 && tid < 256) { bcl[tid-160]=biasc[tid-160]; csl[tid-160]=colsumT[tid-160]; }
  int lane = tid & 63, w = tid >> 6;
  int fr = lane & 15, fg = lane >> 4;
  int wr = w & 1, wc = w >> 1;     // wave: rows wr*16..+15, cols wc*48..+47
  int ra = tid>>3, ca = tid&7;     // A chunk (32 rows x 8 chunks)
  int rb0 = tid>>3,       cb0_ = tid&7;
  int rb1 = (tid+256)>>3, cb1_ = (tid+256)&7;
  int rb2 = (tid+512)>>3, cb2_ = (tid+512)&7;
  f32x4 acc[3];
  #pragma unroll
  for (int n=0;n<3;++n) acc[n] = (f32x4){0.f,0.f,0.f,0.f};

  uint4 ar, br[3];
  auto LOAD = [&](int ks){
    if (ks < 8) {
      int kofs = ks*64;
      ar    = *(const uint4*)&tbf[(size_t)(row0+ra)*512 + kofs + ca*8];
      br[0] = *(const uint4*)&Wtf[(size_t)rb0*512 + kofs + cb0_*8];
      br[1] = *(const uint4*)&Wtf[(size_t)rb1*512 + kofs + cb1_*8];
      br[2] = *(const uint4*)&Wtf[(size_t)rb2*512 + kofs + cb2_*8];
    } else {
      int kofs = (ks-8)*64;
      ar    = *(const uint4*)&ybf[(size_t)(row0+ra)*1024 + kofs + ca*8];
      br[0] = *(const uint4*)&Wsf[(size_t)rb0*1024 + kofs + cb0_*8];
      br[1] = *(const uint4*)&Wsf[(size_t)rb1*1024 + kofs + cb1_*8];
      br[2] = *(const uint4*)&Wsf[(size_t)rb2*1024 + kofs + cb2_*8];
    }
  };

  LOAD(0);
  int cur = 0;
  for (int ks=0; ks<24; ++ks) {
    __hip_bfloat16* Ab = &As[cur*32*72];
    __hip_bfloat16* Bb = &Bs[cur*96*72];
    *(uint4*)&Ab[ra*72 + ca*8] = ar;
    *(uint4*)&Bb[rb0*72 + cb0_*8] = br[0];
    *(uint4*)&Bb[rb1*72 + cb1_*8] = br[1];
    *(uint4*)&Bb[rb2*72 + cb2_*8] = br[2];
    __syncthreads();
    if (ks < 23) LOAD(ks+1);
    #pragma unroll
    for (int ksub=0; ksub<2; ++ksub) {
      bf16x8 av = *(bf16x8*)&Ab[(wr*16+fr)*72 + ksub*32 + fg*8];
      #pragma unroll
      for (int nn=0;nn<3;++nn) {
        int n16 = wc*3 + nn;
        bf16x8 bv = *(bf16x8*)&Bb[(n16*16+fr)*72 + ksub*32 + fg*8];
        acc[nn] = __builtin_amdgcn_mfma_f32_16x16x32_bf16(av, bv, acc[nn], 0,0,0);
      }
    }
    cur ^= 1;
  }
  #pragma unroll
  for (int nn=0;nn<3;++nn) {
    int col = (wc*3+nn)*16 + fr;
    float cs = csl[col], bc = bcl[col];
    #pragma unroll
    for (int reg=0;reg<4;++reg) {
      int rloc = wr*16 + fg*4 + reg;
      float g = rp[rloc*4+1], meanv = rp[rloc*4+2], inva = rp[rloc*4+3];
      float val = acc[nn][reg] + g*cs + bc;
      val = (val - rbl[rloc])*inva + meanv;
      out[(size_t)obase[rloc] + (size_t)col*C_] = val;
    }
  }
}

extern "C" void kernel_launch(void* const* d_in, const int* in_sizes, int n_in,
                              void* d_out, int out_size, void* d_ws, size_t ws_size,
                              hipStream_t stream) {
  const float* x      = (const float*)d_in[0];
  const float* rev_w  = (const float*)d_in[1];
  const float* rev_b  = (const float*)d_in[2];
  const float* fc1_w  = (const float*)d_in[3];
  const float* fc1_b  = (const float*)d_in[4];
  const float* bn1_w  = (const float*)d_in[5];
  const float* bn1_b  = (const float*)d_in[6];
  const float* conv_w = (const float*)d_in[7];
  const float* conv_b = (const float*)d_in[8];
  const float* bn2_w  = (const float*)d_in[9];
  const float* bn2_b  = (const float*)d_in[10];
  const float* fc2_w  = (const float*)d_in[11];
  const float* fc2_b  = (const float*)d_in[12];
  const float* m1_w   = (const float*)d_in[13];
  const float* m1_b   = (const float*)d_in[14];
  const float* m2_w   = (const float*)d_in[15];
  const float* m2_b   = (const float*)d_in[16];
  const float* gl     = (const float*)d_in[17];
  const float* ln_w   = (const float*)d_in[18];
  const float* ln_b   = (const float*)d_in[19];
  const float* seas_w = (const float*)d_in[20];
  const float* seas_b = (const float*)d_in[21];
  const float* tr_w   = (const float*)d_in[22];
  const float* tr_b   = (const float*)d_in[23];
  const float* fus_w  = (const float*)d_in[24];
  const float* fus_b  = (const float*)d_in[25];
  float* out = (float*)d_out;
  float* ws = (float*)d_ws;

  __hip_bfloat16* Wsf  = (__hip_bfloat16*)(ws);
  __hip_bfloat16* Wtf  = (__hip_bfloat16*)(ws + 49152);
  float* biasc   = ws + 73728;
  float* colsumT = ws + 73856;
  float* scale1  = ws + 73984;
  float* shift1  = ws + 74048;
  float* scale2  = ws + 74112;
  float* shift2  = ws + 74176;
  float* partials= ws + 74240;
  float* rowpar  = ws + 238592;
  float* s_raw   = ws + 320768;
  __hip_bfloat16* t_bf = (__hip_bfloat16*)(ws + 11168000);
  __hip_bfloat16* ybf  = (__hip_bfloat16*)(ws + 16427264);
  float* pooled  = ws + 26945792;
  float* wl_g    = ws + 28260608;
  __hip_bfloat16* crp  = (__hip_bfloat16*)(ws + 29575424);  // BC*2048 bf16
  const size_t NEED = (29575424ull + 21037056ull) * 4ull;   // ~202.5 MB
  bool big = (ws_size >= NEED);

  hipLaunchKernelGGL(k0_fold,  dim3(576),  dim3(256), 0, stream, seas_w, tr_w, fus_w, Wsf, Wtf);
  hipLaunchKernelGGL(k0b_bias, dim3(1),    dim3(128), 0, stream, seas_b, tr_b, fus_w, fus_b, tr_w, biasc, colsumT);
  hipLaunchKernelGGL(k1_revin_ema, dim3(BC_/32), dim3(256), 0, stream, x, rev_w, rev_b, s_raw, t_bf, rowpar, pooled);
  hipLaunchKernelGGL(k4_gate, dim3(BC_/64), dim3(256), 0, stream, pooled, m1_w, m1_b, m2_w, m2_b, wl_g);
  if (big) {
    hipLaunchKernelGGL(k2v2_bn1_cr, dim3(NBLK2_), dim3(512), 0, stream, s_raw, fc1_w, fc1_b, conv_w, partials, crp);
    hipLaunchKernelGGL(k_bnreduce, dim3(64), dim3(256), 0, stream, partials, NBLK2_, bn1_w, bn1_b, scale1, shift1);
    hipLaunchKernelGGL(k3v2_bn2stats, dim3(NBLK2_), dim3(512), 0, stream, crp, scale1, shift1, conv_w, conv_b, partials);
    hipLaunchKernelGGL(k_bnreduce, dim3(64), dim3(256), 0, stream, partials, NBLK2_, bn2_w, bn2_b, scale2, shift2);
    hipLaunchKernelGGL(k5a_v2, dim3(BC_/RB_), dim3(512), 0, stream,
      s_raw, wl_g, crp, scale1, shift1, conv_w, conv_b,
      scale2, shift2, fc2_w, fc2_b, gl, ln_w, ln_b, ybf);
  } else {
    hipLaunchKernelGGL(k2_bn1stats, dim3(NBLK2_), dim3(256), 0, stream, s_raw, fc1_w, fc1_b, partials);
    hipLaunchKernelGGL(k_bnreduce, dim3(64), dim3(256), 0, stream, partials, NBLK2_, bn1_w, bn1_b, scale1, shift1);
    hipLaunchKernelGGL(k3_bn2stats, dim3(NBLK2_), dim3(256), 0, stream, s_raw, fc1_w, fc1_b, scale1, shift1, conv_w, conv_b, partials);
    hipLaunchKernelGGL(k_bnreduce, dim3(64), dim3(256), 0, stream, partials, NBLK2_, bn2_w, bn2_b, scale2, shift2);
    hipLaunchKernelGGL(k5a_pipeline, dim3(BC_/RB_), dim3(256), 0, stream,
      s_raw, wl_g, fc1_w, fc1_b, scale1, shift1, conv_w, conv_b,
      scale2, shift2, fc2_w, fc2_b, gl, ln_w, ln_b, ybf);
  }
  hipLaunchKernelGGL(k5b_gemm, dim3(BC_/32), dim3(256), 0, stream,
    ybf, t_bf, Wsf, Wtf, rowpar, rev_b, biasc, colsumT, out);
}